// Round 6
// baseline (5797.755 us; speedup 1.0000x reference)
//
#include <hip/hip_runtime.h>
#include <stdint.h>

// ---------------------------------------------------------------------------
// GRU encoder (B=128,T=512,D=512,H=512,L=256), MI355X gfx950.
//
// R10: R9 resubmitted (container died before the bench's first message —
// infra-shaped failure) with one hardening change: the flag poll escalates
// after 64 relaxed tries to the R4-proven system-scope (sc0 sc1) asm poll,
// which unconditionally observes the latest value. Worst case is therefore
// R4-speed, never a hang — regardless of relaxed-atomic visibility details.
//
// Sync design (HIP/LLVM memory model, agent scope):
//   producer: plain cached h stores -> fence(release,"agent")
//             [s_waitcnt on L2 acks + dirty-L2 writeback to IF$]
//             -> relaxed agent flag store (lane 0).
//   consumer: relaxed agent poll (sc1 coherence-point loads; bounded
//             escalation to sc0 sc1) -> fence(acquire,"agent") [L1/L2 inv]
//             -> plain cached h loads (L2 fill; waves sharing rows share
//             lines).
// R4/R8 counters proved the old system-scope path wrote every h store
// through to HBM (WRITE_SIZE == h volume) and bypassed caches on every h
// load; this keeps the h ring at L2/IF$ latency instead.
// t=0 synthesizes h_0=0 in registers (no hbuf memset; verified R6/R8).
// Topology unchanged from R4: 4 groups x 2 row-halves, 32 producer-wave
// flags per half; release-then-flag, poll-then-acquire-then-load induction.
// ---------------------------------------------------------------------------

typedef short short8 __attribute__((ext_vector_type(8)));
typedef float f32x4 __attribute__((ext_vector_type(4)));

#define NB 128
#define NT 512
#define ND 512
#define NH 512
#define NG 1536  // 3H

__device__ __forceinline__ unsigned short f2bf(float f) {
  union { float f; unsigned u; } v; v.f = f;
  unsigned r = v.u + 0x7fffu + ((v.u >> 16) & 1u);  // RNE
  return (unsigned short)(r >> 16);
}
__device__ __forceinline__ float bf2f(unsigned short u) {
  union { unsigned u; float f; } v; v.u = ((unsigned)u) << 16; return v.f;
}
__device__ __forceinline__ float sigmoid_f(float x) {
  float e = __builtin_amdgcn_exp2f(-1.4426950408889634f * x);
  return __builtin_amdgcn_rcpf(1.0f + e);
}
__device__ __forceinline__ float tanh_f(float x) {
  float e = __builtin_amdgcn_exp2f(2.8853900817779268f * x);
  return 1.0f - 2.0f * __builtin_amdgcn_rcpf(1.0f + e);
}
__device__ __forceinline__ short8 pack8(float4 a, float4 b) {
  short8 s;
  s[0] = (short)f2bf(a.x); s[1] = (short)f2bf(a.y);
  s[2] = (short)f2bf(a.z); s[3] = (short)f2bf(a.w);
  s[4] = (short)f2bf(b.x); s[5] = (short)f2bf(b.y);
  s[6] = (short)f2bf(b.z); s[7] = (short)f2bf(b.w);
  return s;
}

// System-scope poll (R4-proven): unconditionally observes the latest flag.
// Used only as the bounded-escalation fallback.
__device__ __forceinline__ unsigned poll_load_sys(const unsigned* p) {
  unsigned f;
  asm volatile(
      "global_load_dword %0, %1, off sc0 sc1\n\t"
      "s_waitcnt vmcnt(0)"
      : "=v"(f) : "v"(p) : "memory");
  return f;
}

// ---------------------------------------------------------------------------
// IG = x @ Wih^T + bias, bf16 out. M=65536, N=1536, K=512. (unchanged)
// ---------------------------------------------------------------------------
__global__ __launch_bounds__(256) void ig_gemm(
    const float* __restrict__ x, const float* __restrict__ Wih,
    const float* __restrict__ bias, unsigned short* __restrict__ IG) {
  __shared__ unsigned short As[128 * 40];
  __shared__ unsigned short Bs[128 * 40];
  const int tid = threadIdx.x;
  const int bm = blockIdx.x, bn = blockIdx.y;
  const int lane = tid & 63, w = tid >> 6;
  const int wm = w >> 1, wn = w & 1;
  const int l15 = lane & 15, q = lane >> 4;

  f32x4 acc[4][4] = {};

  for (int kt = 0; kt < 16; ++kt) {
    __syncthreads();
#pragma unroll
    for (int j = 0; j < 4; ++j) {
      int fi = tid + 256 * j;
      int row = fi >> 3, kq = fi & 7;
      float4 v = *(const float4*)(x + (size_t)(bm * 128 + row) * ND + kt * 32 + kq * 4);
      ushort4 s = {f2bf(v.x), f2bf(v.y), f2bf(v.z), f2bf(v.w)};
      *(ushort4*)&As[row * 40 + kq * 4] = s;
    }
#pragma unroll
    for (int j = 0; j < 4; ++j) {
      int fi = tid + 256 * j;
      int row = fi >> 3, kq = fi & 7;
      float4 v = *(const float4*)(Wih + (size_t)(bn * 128 + row) * ND + kt * 32 + kq * 4);
      ushort4 s = {f2bf(v.x), f2bf(v.y), f2bf(v.z), f2bf(v.w)};
      *(ushort4*)&Bs[row * 40 + kq * 4] = s;
    }
    __syncthreads();

    short8 af[4], bfv[4];
#pragma unroll
    for (int tm = 0; tm < 4; ++tm)
      af[tm] = *(const short8*)&As[(wm * 64 + tm * 16 + l15) * 40 + q * 8];
#pragma unroll
    for (int tn = 0; tn < 4; ++tn)
      bfv[tn] = *(const short8*)&Bs[(wn * 64 + tn * 16 + l15) * 40 + q * 8];
#pragma unroll
    for (int tm = 0; tm < 4; ++tm)
#pragma unroll
      for (int tn = 0; tn < 4; ++tn)
        acc[tm][tn] = __builtin_amdgcn_mfma_f32_16x16x32_bf16(af[tm], bfv[tn], acc[tm][tn], 0, 0, 0);
  }

#pragma unroll
  for (int tm = 0; tm < 4; ++tm) {
#pragma unroll
    for (int tn = 0; tn < 4; ++tn) {
      int col = bn * 128 + wn * 64 + tn * 16 + l15;
      float bb = bias[col];
#pragma unroll
      for (int i = 0; i < 4; ++i) {
        int row = bm * 128 + wm * 64 + tm * 16 + q * 4 + i;
        IG[(size_t)row * NG + col] = f2bf(acc[tm][tn][i] + bb);
      }
    }
  }
}

// ---------------------------------------------------------------------------
// Persistent GRU recurrence. 64 blocks x 256 threads. (R4 topology)
// block = (group g of 32 batch rows, chunk c of 32 h-cols).
// wave (wm,wn): rows [b0+wm*16, +16), cols [c*32+wn*16, +16).
// flags[((g*2+wm)*16+c)*2+wn] = step count published by that producer wave
// (release fence before flag; acquire fence after poll).
// ---------------------------------------------------------------------------
template <bool USE_IG>
__global__ __launch_bounds__(256, 1) void gru_rec(
    const float* __restrict__ x, const float* __restrict__ Wih,
    const float* __restrict__ Whh, const float* __restrict__ bias,
    const float* __restrict__ bn, const unsigned short* __restrict__ IG,
    unsigned short* __restrict__ hbuf, unsigned* __restrict__ flags,
    float* __restrict__ hfin) {
  const int tid = threadIdx.x;
  const int lane = tid & 63;
  const int w = tid >> 6;
  const int wm = w >> 1, wn = w & 1;
  const int l15 = lane & 15, q = lane >> 4;
  const int g = blockIdx.x >> 4;   // 4 groups
  const int c = blockIdx.x & 15;   // 16 col-chunks of 32
  const int b0 = g * 32;
  const int col = c * 32 + wn * 16 + l15;  // this lane's h column
  const int mrow = b0 + wm * 16 + l15;     // A-fragment batch row
  const int erow = b0 + wm * 16 + q * 4;   // C-layout batch row base

  unsigned* const myflag = flags + ((g * 2 + wm) * 16 + c) * 2 + wn;
  const unsigned* const pollbase = flags + (g * 2 + wm) * 32;  // 32 flags

  // Whh B-fragments -> registers: 3 gates x 16 k-chunks (192 VGPRs)
  short8 bfr[3][16];
#pragma unroll
  for (int gt = 0; gt < 3; ++gt) {
    const float* src = Whh + (size_t)(gt * NH + col) * NH + q * 8;
#pragma unroll
    for (int kk = 0; kk < 16; ++kk) {
      float4 v0 = *(const float4*)(src + kk * 32);
      float4 v1 = *(const float4*)(src + kk * 32 + 4);
      bfr[gt][kk] = pack8(v0, v1);
    }
  }

  float bi_r = 0.f, bi_z = 0.f, bi_n = 0.f;
  if (!USE_IG) {
    bi_r = bias[col];
    bi_z = bias[NH + col];
    bi_n = bias[2 * NH + col];
  }
  const float bnv = bn[col];

  float hreg[4] = {0.f, 0.f, 0.f, 0.f};

  unsigned short* const hb0 = hbuf;
  unsigned short* const hb1 = hbuf + NB * NH;

  for (int t = 0; t < NT; ++t) {
    const unsigned short* hcur = (t & 1) ? hb1 : hb0;
    unsigned short* hnxt = (t & 1) ? hb0 : hb1;

    short8 araw[16];
    if (t > 0) {
      // wait for the 32 producer waves of this row-half to have published h_t
      if (lane < 32) {
        const unsigned* fp = pollbase + lane;
        unsigned f = __hip_atomic_load(fp, __ATOMIC_RELAXED,
                                       __HIP_MEMORY_SCOPE_AGENT);
        int tries = 0;
        while ((int)f < t) {
          // bounded escalation: after 64 relaxed tries, use the R4-proven
          // system-scope poll (guaranteed-fresh). Cannot hang.
          if (++tries > 64)
            f = poll_load_sys(fp);
          else
            f = __hip_atomic_load(fp, __ATOMIC_RELAXED,
                                  __HIP_MEMORY_SCOPE_AGENT);
        }
      }
      // one acquire fence for the wave: invalidates stale L1/L2 lines so the
      // plain cached loads below observe the producers' released stores.
      __builtin_amdgcn_fence(__ATOMIC_ACQUIRE, "agent");
      const short8* hp = (const short8*)(hcur + (size_t)mrow * NH + q * 8);
#pragma unroll
      for (int kk = 0; kk < 16; ++kk) araw[kk] = hp[kk * 4];  // stride 32 elems
    } else {
      // h_0 = 0: no poll, no load
#pragma unroll
      for (int kk = 0; kk < 16; ++kk)
        araw[kk] = (short8){0, 0, 0, 0, 0, 0, 0, 0};
    }

    // IG loads (plain cached); issued post-fence, hide under the MFMA chain.
    float igr[4], igz[4], ignv[4];
    if (USE_IG) {
#pragma unroll
      for (int i = 0; i < 4; ++i) {
        const size_t base = ((size_t)(erow + i) * NT + t) * NG + col;
        igr[i] = bf2f(IG[base]);
        igz[i] = bf2f(IG[base + NH]);
        ignv[i] = bf2f(IG[base + 2 * NH]);
      }
    }

    f32x4 ar = {0.f, 0.f, 0.f, 0.f};
    f32x4 az = {0.f, 0.f, 0.f, 0.f};
    f32x4 an = {0.f, 0.f, 0.f, 0.f};
    f32x4 ai = {0.f, 0.f, 0.f, 0.f};
#pragma unroll
    for (int kk = 0; kk < 16; ++kk) {
      ar = __builtin_amdgcn_mfma_f32_16x16x32_bf16(araw[kk], bfr[0][kk], ar, 0, 0, 0);
      az = __builtin_amdgcn_mfma_f32_16x16x32_bf16(araw[kk], bfr[1][kk], az, 0, 0, 0);
      an = __builtin_amdgcn_mfma_f32_16x16x32_bf16(araw[kk], bfr[2][kk], an, 0, 0, 0);
      if (!USE_IG) {
        const float* xp = x + ((size_t)mrow * NT + t) * ND + kk * 32 + q * 8;
        short8 xa = pack8(*(const float4*)xp, *(const float4*)(xp + 4));
#pragma unroll
        for (int gt = 0; gt < 3; ++gt) {
          const float* wp = Wih + (size_t)(gt * NH + col) * ND + kk * 32 + q * 8;
          short8 wf = pack8(*(const float4*)wp, *(const float4*)(wp + 4));
          if (gt == 0) ar = __builtin_amdgcn_mfma_f32_16x16x32_bf16(xa, wf, ar, 0, 0, 0);
          if (gt == 1) az = __builtin_amdgcn_mfma_f32_16x16x32_bf16(xa, wf, az, 0, 0, 0);
          if (gt == 2) ai = __builtin_amdgcn_mfma_f32_16x16x32_bf16(xa, wf, ai, 0, 0, 0);
        }
      }
    }

    // gates + h update; plain cached stores, then release fence + flag
#pragma unroll
    for (int i = 0; i < 4; ++i) {
      float xr = USE_IG ? (ar[i] + igr[i]) : (ar[i] + bi_r);
      float xz = USE_IG ? (az[i] + igz[i]) : (az[i] + bi_z);
      float xin = USE_IG ? ignv[i] : (ai[i] + bi_n);
      float r = sigmoid_f(xr);
      float z = sigmoid_f(xz);
      float n = tanh_f(xin + r * (an[i] + bnv));
      float hn2 = (1.f - z) * n + z * hreg[i];
      hreg[i] = hn2;
      if (t == NT - 1) {
        hfin[(size_t)(erow + i) * NH + col] = hn2;
      } else {
        hnxt[(size_t)(erow + i) * NH + col] = f2bf(hn2);
      }
    }
    if (t != NT - 1) {
      // release: drain this wave's h stores (L2 acks) + write back dirty L2
      // so the relaxed flag store implies agent-wide visibility of h_{t+1}.
      __builtin_amdgcn_fence(__ATOMIC_RELEASE, "agent");
      if (lane == 0)
        __hip_atomic_store(myflag, (unsigned)(t + 1), __ATOMIC_RELAXED,
                           __HIP_MEMORY_SCOPE_AGENT);
    }
  }
}

// ---------------------------------------------------------------------------
// out = h_T @ Wlin^T + blin; mu = cols [0,256), logvar = cols [256,512).
// ---------------------------------------------------------------------------
__global__ __launch_bounds__(256) void final_linear(
    const float* __restrict__ hfin, const float* __restrict__ Wlin,
    const float* __restrict__ blin, float* __restrict__ out) {
  __shared__ float sh[16 * 516];
  const int tid = threadIdx.x;
  const int b0 = blockIdx.y * 16, o0 = blockIdx.x * 16;

  for (int j = tid; j < 16 * 128; j += 256) {
    int row = j >> 7, kq = j & 127;
    *(float4*)&sh[row * 516 + kq * 4] =
        *(const float4*)(hfin + (size_t)(b0 + row) * NH + kq * 4);
  }
  __syncthreads();

  const int bi = tid & 15, oi = tid >> 4;
  const int o = o0 + oi;
  const float4* wp = (const float4*)(Wlin + (size_t)o * NH);
  float4 a4 = {0.f, 0.f, 0.f, 0.f};
  for (int k4 = 0; k4 < 128; ++k4) {
    float4 wv = wp[k4];
    float4 hv = *(const float4*)&sh[bi * 516 + k4 * 4];
    a4.x += wv.x * hv.x; a4.y += wv.y * hv.y;
    a4.z += wv.z * hv.z; a4.w += wv.w * hv.w;
  }
  float v = a4.x + a4.y + a4.z + a4.w + blin[o];
  int b = b0 + bi;
  if (o < 256) out[b * 256 + o] = v;
  else out[32768 + b * 256 + (o - 256)] = v;
}

// ---------------------------------------------------------------------------
extern "C" void kernel_launch(void* const* d_in, const int* in_sizes, int n_in,
                              void* d_out, int out_size, void* d_ws, size_t ws_size,
                              hipStream_t stream) {
  const float* x    = (const float*)d_in[0];
  const float* Wih  = (const float*)d_in[1];
  const float* Whh  = (const float*)d_in[2];
  const float* bias = (const float*)d_in[3];
  const float* bn   = (const float*)d_in[4];
  const float* Wlin = (const float*)d_in[5];
  const float* blin = (const float*)d_in[6];
  float* out = (float*)d_out;

  char* ws = (char*)d_ws;
  // layout: [hbuf 262144][flags 1024][hfin 262144][IG 201326592]
  unsigned short* hbuf = (unsigned short*)ws;
  unsigned* flags      = (unsigned*)(ws + 262144);
  float* hfin          = (float*)(ws + 263168);
  unsigned short* IG   = (unsigned short*)(ws + 525312);
  const size_t need_min = 525312;
  const size_t need_ig  = 525312 + (size_t)NB * NT * NG * 2;  // ~203 MB
  if (ws_size < need_min) return;

  // zero flags only (h_0 is synthesized in registers; hbuf needs no init)
  hipMemsetAsync(ws + 262144, 0, 1024, stream);

  const bool useIG = (ws_size >= need_ig);
  if (useIG) {
    ig_gemm<<<dim3(512, 12), 256, 0, stream>>>(x, Wih, bias, IG);
    gru_rec<true><<<64, 256, 0, stream>>>(x, Wih, Whh, bias, bn, IG, hbuf, flags, hfin);
  } else {
    gru_rec<false><<<64, 256, 0, stream>>>(x, Wih, Whh, bias, bn, nullptr, hbuf, flags, hfin);
  }
  final_linear<<<dim3(32, 8), 256, 0, stream>>>(hfin, Wlin, blin, out);
}

// Round 7
// 4729.029 us; speedup vs baseline: 1.2260x; 1.2260x over previous
//
#include <hip/hip_runtime.h>
#include <stdint.h>

// ---------------------------------------------------------------------------
// GRU encoder (B=128,T=512,D=512,H=512,L=256), MI355X gfx950.
//
// R11: TAGGED-DATA sync. h is stored as u32 words: (bf16 value << 16) | tag,
// tag = step index of the h version (h_t carries tag t). 32-bit stores are
// atomic -> value+tag cannot tear.
//   producer: gates -> 4 tagged sc0 sc1 dword stores -> CONTINUE (no drain,
//             no flag store).
//   consumer: load all 16x8 tagged dwords (sc0 sc1), verify 128 tags == t,
//             reload until clean. The load IS the poll; poll-RT and data-RT
//             collapse into one, and the producer drain-RT disappears.
// Induction (overwrite safety) unchanged in strength: a tag-verified read of
// h_t covers all 32 producer tiles of the row-half, so a wave storing
// h_{t+1} proves all waves finished reading h_{t-1} from that buffer.
// Deadlock-free by construction: stores are eventually visible; consumer
// retries until then (worst case ~R4 speed, never hung).
// Lessons baked in: R5/R7 (raw scope bits) and R9/R10 (agent fences ->
// wbl2/inv storms, 2.7x regression, WRITE_SIZE unchanged) prove per-access
// sc0 sc1 coherent ops are the only fast+correct publication path here;
// what this round removes is the NUMBER of serial RTs, not their scope.
// hbuf (u32, both buffers) memset to 0 each launch so garbage can't alias
// a valid tag (tags start at 1). t=0 synthesizes h_0 = 0 in registers.
// ---------------------------------------------------------------------------

typedef short short8 __attribute__((ext_vector_type(8)));
typedef float f32x4 __attribute__((ext_vector_type(4)));
typedef int int4v __attribute__((ext_vector_type(4)));

#define NB 128
#define NT 512
#define ND 512
#define NH 512
#define NG 1536  // 3H

__device__ __forceinline__ unsigned short f2bf(float f) {
  union { float f; unsigned u; } v; v.f = f;
  unsigned r = v.u + 0x7fffu + ((v.u >> 16) & 1u);  // RNE
  return (unsigned short)(r >> 16);
}
__device__ __forceinline__ float bf2f(unsigned short u) {
  union { unsigned u; float f; } v; v.u = ((unsigned)u) << 16; return v.f;
}
__device__ __forceinline__ float sigmoid_f(float x) {
  float e = __builtin_amdgcn_exp2f(-1.4426950408889634f * x);
  return __builtin_amdgcn_rcpf(1.0f + e);
}
__device__ __forceinline__ float tanh_f(float x) {
  float e = __builtin_amdgcn_exp2f(2.8853900817779268f * x);
  return 1.0f - 2.0f * __builtin_amdgcn_rcpf(1.0f + e);
}
__device__ __forceinline__ short8 pack8(float4 a, float4 b) {
  short8 s;
  s[0] = (short)f2bf(a.x); s[1] = (short)f2bf(a.y);
  s[2] = (short)f2bf(a.z); s[3] = (short)f2bf(a.w);
  s[4] = (short)f2bf(b.x); s[5] = (short)f2bf(b.y);
  s[6] = (short)f2bf(b.z); s[7] = (short)f2bf(b.w);
  return s;
}

// 16 coherent dwordx4 loads covering 8 tagged chunks (kk .. kk+7):
// chunk k at byte offsets k*128 and k*128+16 from the lane pointer.
__device__ __forceinline__ void load_t16x4(const unsigned* p, int4v a[16]) {
  asm volatile(
      "global_load_dwordx4 %0,  %16, off sc0 sc1\n\t"
      "global_load_dwordx4 %1,  %16, off offset:16 sc0 sc1\n\t"
      "global_load_dwordx4 %2,  %16, off offset:128 sc0 sc1\n\t"
      "global_load_dwordx4 %3,  %16, off offset:144 sc0 sc1\n\t"
      "global_load_dwordx4 %4,  %16, off offset:256 sc0 sc1\n\t"
      "global_load_dwordx4 %5,  %16, off offset:272 sc0 sc1\n\t"
      "global_load_dwordx4 %6,  %16, off offset:384 sc0 sc1\n\t"
      "global_load_dwordx4 %7,  %16, off offset:400 sc0 sc1\n\t"
      "global_load_dwordx4 %8,  %16, off offset:512 sc0 sc1\n\t"
      "global_load_dwordx4 %9,  %16, off offset:528 sc0 sc1\n\t"
      "global_load_dwordx4 %10, %16, off offset:640 sc0 sc1\n\t"
      "global_load_dwordx4 %11, %16, off offset:656 sc0 sc1\n\t"
      "global_load_dwordx4 %12, %16, off offset:768 sc0 sc1\n\t"
      "global_load_dwordx4 %13, %16, off offset:784 sc0 sc1\n\t"
      "global_load_dwordx4 %14, %16, off offset:896 sc0 sc1\n\t"
      "global_load_dwordx4 %15, %16, off offset:912 sc0 sc1\n\t"
      "s_waitcnt vmcnt(0)"
      : "=&v"(a[0]), "=&v"(a[1]), "=&v"(a[2]), "=&v"(a[3]),
        "=&v"(a[4]), "=&v"(a[5]), "=&v"(a[6]), "=&v"(a[7]),
        "=&v"(a[8]), "=&v"(a[9]), "=&v"(a[10]), "=&v"(a[11]),
        "=&v"(a[12]), "=&v"(a[13]), "=&v"(a[14]), "=&v"(a[15])
      : "v"(p)
      : "memory");
}

// 4 tagged dword stores (rows erow..erow+3). Base pre-offset by +2 rows so
// the 13-bit signed offsets cover row stride 512*4B = 2048B. NO drain.
__device__ __forceinline__ void store_t4(unsigned* p2, unsigned v0,
                                         unsigned v1, unsigned v2, unsigned v3) {
  asm volatile(
      "global_store_dword %0, %1, off offset:-4096 sc0 sc1\n\t"
      "global_store_dword %0, %2, off offset:-2048 sc0 sc1\n\t"
      "global_store_dword %0, %3, off sc0 sc1\n\t"
      "global_store_dword %0, %4, off offset:2048 sc0 sc1"
      :
      : "v"(p2), "v"(v0), "v"(v1), "v"(v2), "v"(v3)
      : "memory");
}

// ---------------------------------------------------------------------------
// IG = x @ Wih^T + bias, bf16 out. M=65536, N=1536, K=512. (unchanged)
// ---------------------------------------------------------------------------
__global__ __launch_bounds__(256) void ig_gemm(
    const float* __restrict__ x, const float* __restrict__ Wih,
    const float* __restrict__ bias, unsigned short* __restrict__ IG) {
  __shared__ unsigned short As[128 * 40];
  __shared__ unsigned short Bs[128 * 40];
  const int tid = threadIdx.x;
  const int bm = blockIdx.x, bn = blockIdx.y;
  const int lane = tid & 63, w = tid >> 6;
  const int wm = w >> 1, wn = w & 1;
  const int l15 = lane & 15, q = lane >> 4;

  f32x4 acc[4][4] = {};

  for (int kt = 0; kt < 16; ++kt) {
    __syncthreads();
#pragma unroll
    for (int j = 0; j < 4; ++j) {
      int fi = tid + 256 * j;
      int row = fi >> 3, kq = fi & 7;
      float4 v = *(const float4*)(x + (size_t)(bm * 128 + row) * ND + kt * 32 + kq * 4);
      ushort4 s = {f2bf(v.x), f2bf(v.y), f2bf(v.z), f2bf(v.w)};
      *(ushort4*)&As[row * 40 + kq * 4] = s;
    }
#pragma unroll
    for (int j = 0; j < 4; ++j) {
      int fi = tid + 256 * j;
      int row = fi >> 3, kq = fi & 7;
      float4 v = *(const float4*)(Wih + (size_t)(bn * 128 + row) * ND + kt * 32 + kq * 4);
      ushort4 s = {f2bf(v.x), f2bf(v.y), f2bf(v.z), f2bf(v.w)};
      *(ushort4*)&Bs[row * 40 + kq * 4] = s;
    }
    __syncthreads();

    short8 af[4], bfv[4];
#pragma unroll
    for (int tm = 0; tm < 4; ++tm)
      af[tm] = *(const short8*)&As[(wm * 64 + tm * 16 + l15) * 40 + q * 8];
#pragma unroll
    for (int tn = 0; tn < 4; ++tn)
      bfv[tn] = *(const short8*)&Bs[(wn * 64 + tn * 16 + l15) * 40 + q * 8];
#pragma unroll
    for (int tm = 0; tm < 4; ++tm)
#pragma unroll
      for (int tn = 0; tn < 4; ++tn)
        acc[tm][tn] = __builtin_amdgcn_mfma_f32_16x16x32_bf16(af[tm], bfv[tn], acc[tm][tn], 0, 0, 0);
  }

#pragma unroll
  for (int tm = 0; tm < 4; ++tm) {
#pragma unroll
    for (int tn = 0; tn < 4; ++tn) {
      int col = bn * 128 + wn * 64 + tn * 16 + l15;
      float bb = bias[col];
#pragma unroll
      for (int i = 0; i < 4; ++i) {
        int row = bm * 128 + wm * 64 + tm * 16 + q * 4 + i;
        IG[(size_t)row * NG + col] = f2bf(acc[tm][tn][i] + bb);
      }
    }
  }
}

// ---------------------------------------------------------------------------
// Persistent GRU recurrence. 64 blocks x 256 threads. (R4 topology)
// block = (group g of 32 batch rows, chunk c of 32 h-cols).
// wave (wm,wn): rows [b0+wm*16, +16), cols [c*32+wn*16, +16).
// h buffers are u32 tagged words; no flag array exists.
// ---------------------------------------------------------------------------
template <bool USE_IG>
__global__ __launch_bounds__(256, 1) void gru_rec(
    const float* __restrict__ x, const float* __restrict__ Wih,
    const float* __restrict__ Whh, const float* __restrict__ bias,
    const float* __restrict__ bn, const unsigned short* __restrict__ IG,
    unsigned* __restrict__ hbuf, float* __restrict__ hfin) {
  const int tid = threadIdx.x;
  const int lane = tid & 63;
  const int w = tid >> 6;
  const int wm = w >> 1, wn = w & 1;
  const int l15 = lane & 15, q = lane >> 4;
  const int g = blockIdx.x >> 4;   // 4 groups
  const int c = blockIdx.x & 15;   // 16 col-chunks of 32
  const int b0 = g * 32;
  const int col = c * 32 + wn * 16 + l15;  // this lane's h column
  const int mrow = b0 + wm * 16 + l15;     // A-fragment batch row
  const int erow = b0 + wm * 16 + q * 4;   // C-layout batch row base

  // Whh B-fragments -> registers: 3 gates x 16 k-chunks (192 VGPRs)
  short8 bfr[3][16];
#pragma unroll
  for (int gt = 0; gt < 3; ++gt) {
    const float* src = Whh + (size_t)(gt * NH + col) * NH + q * 8;
#pragma unroll
    for (int kk = 0; kk < 16; ++kk) {
      float4 v0 = *(const float4*)(src + kk * 32);
      float4 v1 = *(const float4*)(src + kk * 32 + 4);
      bfr[gt][kk] = pack8(v0, v1);
    }
  }

  float bi_r = 0.f, bi_z = 0.f, bi_n = 0.f;
  if (!USE_IG) {
    bi_r = bias[col];
    bi_z = bias[NH + col];
    bi_n = bias[2 * NH + col];
  }
  const float bnv = bn[col];

  float hreg[4] = {0.f, 0.f, 0.f, 0.f};

  unsigned* const hb0 = hbuf;
  unsigned* const hb1 = hbuf + NB * NH;

  for (int t = 0; t < NT; ++t) {
    const unsigned* hcur = (t & 1) ? hb1 : hb0;
    unsigned* hnxt = (t & 1) ? hb0 : hb1;

    // ---- acquire h_t: tagged loads, verify 128 tags == t, retry until clean
    int4v a0[16], a1[16];
    if (t > 0) {
      const unsigned* hp = hcur + (size_t)mrow * NH + q * 8;
      unsigned bad;
      do {
        load_t16x4(hp, a0);          // chunks kk = 0..7
        load_t16x4(hp + 256, a1);    // chunks kk = 8..15
        bad = 0;
        const unsigned tt = (unsigned)t;
#pragma unroll
        for (int i = 0; i < 16; ++i) {
#pragma unroll
          for (int j = 0; j < 4; ++j) {
            bad |= ((unsigned)a0[i][j] ^ tt) & 0xffffu;
            bad |= ((unsigned)a1[i][j] ^ tt) & 0xffffu;
          }
        }
      } while (__builtin_expect(bad != 0, 0));
    } else {
      // h_0 = 0 (memset'd buffers are never read at t=0)
#pragma unroll
      for (int i = 0; i < 16; ++i) {
        a0[i] = (int4v){0, 0, 0, 0};
        a1[i] = (int4v){0, 0, 0, 0};
      }
    }

    // IG loads (plain cached); issued after verify so the verify vmcnt(0)
    // never waits on them; latency hides under pack+MFMA+gates.
    float igr[4], igz[4], ignv[4];
    if (USE_IG) {
#pragma unroll
      for (int i = 0; i < 4; ++i) {
        const size_t base = ((size_t)(erow + i) * NT + t) * NG + col;
        igr[i] = bf2f(IG[base]);
        igz[i] = bf2f(IG[base + NH]);
        ignv[i] = bf2f(IG[base + 2 * NH]);
      }
    }

    f32x4 ar = {0.f, 0.f, 0.f, 0.f};
    f32x4 az = {0.f, 0.f, 0.f, 0.f};
    f32x4 an = {0.f, 0.f, 0.f, 0.f};
    f32x4 ai = {0.f, 0.f, 0.f, 0.f};
#pragma unroll
    for (int kk = 0; kk < 16; ++kk) {
      // repack tagged dwords (value in hi16) -> bf16 short8 fragment
      const int4v dlo = (kk < 8) ? a0[2 * kk] : a1[2 * (kk - 8)];
      const int4v dhi = (kk < 8) ? a0[2 * kk + 1] : a1[2 * (kk - 8) + 1];
      unsigned w0 = __builtin_amdgcn_perm((unsigned)dlo[1], (unsigned)dlo[0], 0x07060302u);
      unsigned w1 = __builtin_amdgcn_perm((unsigned)dlo[3], (unsigned)dlo[2], 0x07060302u);
      unsigned w2 = __builtin_amdgcn_perm((unsigned)dhi[1], (unsigned)dhi[0], 0x07060302u);
      unsigned w3 = __builtin_amdgcn_perm((unsigned)dhi[3], (unsigned)dhi[2], 0x07060302u);
      int4v wv = {(int)w0, (int)w1, (int)w2, (int)w3};
      short8 afk = __builtin_bit_cast(short8, wv);

      ar = __builtin_amdgcn_mfma_f32_16x16x32_bf16(afk, bfr[0][kk], ar, 0, 0, 0);
      az = __builtin_amdgcn_mfma_f32_16x16x32_bf16(afk, bfr[1][kk], az, 0, 0, 0);
      an = __builtin_amdgcn_mfma_f32_16x16x32_bf16(afk, bfr[2][kk], an, 0, 0, 0);
      if (!USE_IG) {
        const float* xp = x + ((size_t)mrow * NT + t) * ND + kk * 32 + q * 8;
        short8 xa = pack8(*(const float4*)xp, *(const float4*)(xp + 4));
#pragma unroll
        for (int gt = 0; gt < 3; ++gt) {
          const float* wp = Wih + (size_t)(gt * NH + col) * ND + kk * 32 + q * 8;
          short8 wf = pack8(*(const float4*)wp, *(const float4*)(wp + 4));
          if (gt == 0) ar = __builtin_amdgcn_mfma_f32_16x16x32_bf16(xa, wf, ar, 0, 0, 0);
          if (gt == 1) az = __builtin_amdgcn_mfma_f32_16x16x32_bf16(xa, wf, az, 0, 0, 0);
          if (gt == 2) ai = __builtin_amdgcn_mfma_f32_16x16x32_bf16(xa, wf, ai, 0, 0, 0);
        }
      }
    }

    // gates + h update; publish tagged h_{t+1} (no drain, no flag)
    unsigned sv[4];
#pragma unroll
    for (int i = 0; i < 4; ++i) {
      float xr = USE_IG ? (ar[i] + igr[i]) : (ar[i] + bi_r);
      float xz = USE_IG ? (az[i] + igz[i]) : (az[i] + bi_z);
      float xin = USE_IG ? ignv[i] : (ai[i] + bi_n);
      float r = sigmoid_f(xr);
      float z = sigmoid_f(xz);
      float n = tanh_f(xin + r * (an[i] + bnv));
      float hn2 = (1.f - z) * n + z * hreg[i];
      hreg[i] = hn2;
      sv[i] = ((unsigned)f2bf(hn2) << 16) | (unsigned)(t + 1);
      if (t == NT - 1) hfin[(size_t)(erow + i) * NH + col] = hn2;
    }
    if (t != NT - 1) {
      unsigned* sp2 = hnxt + (size_t)(erow + 2) * NH + col;  // +2-row base
      store_t4(sp2, sv[0], sv[1], sv[2], sv[3]);
    }
  }
}

// ---------------------------------------------------------------------------
// out = h_T @ Wlin^T + blin; mu = cols [0,256), logvar = cols [256,512).
// ---------------------------------------------------------------------------
__global__ __launch_bounds__(256) void final_linear(
    const float* __restrict__ hfin, const float* __restrict__ Wlin,
    const float* __restrict__ blin, float* __restrict__ out) {
  __shared__ float sh[16 * 516];
  const int tid = threadIdx.x;
  const int b0 = blockIdx.y * 16, o0 = blockIdx.x * 16;

  for (int j = tid; j < 16 * 128; j += 256) {
    int row = j >> 7, kq = j & 127;
    *(float4*)&sh[row * 516 + kq * 4] =
        *(const float4*)(hfin + (size_t)(b0 + row) * NH + kq * 4);
  }
  __syncthreads();

  const int bi = tid & 15, oi = tid >> 4;
  const int o = o0 + oi;
  const float4* wp = (const float4*)(Wlin + (size_t)o * NH);
  float4 a4 = {0.f, 0.f, 0.f, 0.f};
  for (int k4 = 0; k4 < 128; ++k4) {
    float4 wv = wp[k4];
    float4 hv = *(const float4*)&sh[bi * 516 + k4 * 4];
    a4.x += wv.x * hv.x; a4.y += wv.y * hv.y;
    a4.z += wv.z * hv.z; a4.w += wv.w * hv.w;
  }
  float v = a4.x + a4.y + a4.z + a4.w + blin[o];
  int b = b0 + bi;
  if (o < 256) out[b * 256 + o] = v;
  else out[32768 + b * 256 + (o - 256)] = v;
}

// ---------------------------------------------------------------------------
extern "C" void kernel_launch(void* const* d_in, const int* in_sizes, int n_in,
                              void* d_out, int out_size, void* d_ws, size_t ws_size,
                              hipStream_t stream) {
  const float* x    = (const float*)d_in[0];
  const float* Wih  = (const float*)d_in[1];
  const float* Whh  = (const float*)d_in[2];
  const float* bias = (const float*)d_in[3];
  const float* bn   = (const float*)d_in[4];
  const float* Wlin = (const float*)d_in[5];
  const float* blin = (const float*)d_in[6];
  float* out = (float*)d_out;

  char* ws = (char*)d_ws;
  // layout: [hbuf u32 x2 524288][hfin 262144][IG 201326592]
  unsigned* hbuf = (unsigned*)ws;
  float* hfin    = (float*)(ws + 524288);
  unsigned short* IG = (unsigned short*)(ws + 786432);
  const size_t need_min = 786432;
  const size_t need_ig  = 786432 + (size_t)NB * NT * NG * 2;  // ~203 MB
  if (ws_size < need_min) return;

  // zero both tagged h buffers (tag 0 < any live tag; prevents garbage alias)
  hipMemsetAsync(ws, 0, 524288, stream);

  const bool useIG = (ws_size >= need_ig);
  if (useIG) {
    ig_gemm<<<dim3(512, 12), 256, 0, stream>>>(x, Wih, bias, IG);
    gru_rec<true><<<64, 256, 0, stream>>>(x, Wih, Whh, bias, bn, IG, hbuf, hfin);
  } else {
    gru_rec<false><<<64, 256, 0, stream>>>(x, Wih, Whh, bias, bn, nullptr, hbuf, hfin);
  }
  final_linear<<<dim3(32, 8), 256, 0, stream>>>(hfin, Wlin, blin, out);
}

// Round 8
// 4102.289 us; speedup vs baseline: 1.4133x; 1.1528x over previous
//
#include <hip/hip_runtime.h>
#include <stdint.h>

// ---------------------------------------------------------------------------
// GRU encoder (B=128,T=512,D=512,H=512,L=256), MI355X gfx950.
//
// R12: FLAG-GATED TAGGED LOAD. Merges the proven halves of R4 and R11:
//   producer: gates -> 4 tagged u32 h stores (sc0 sc1, NO drain)
//             -> flag=t+1 immediately (no drain). Drain RT leaves the ring;
//             own store-acks are absorbed by the NEXT poll's vmcnt(0)
//             (overlapped with the ring wait — R6's idea done right:
//             flag first, then poll).
//   consumer: R4 cheap flag poll (1 dword/lane) -> ONE batch of 32 tagged
//             dwordx4 loads with a SINGLE vmcnt(0) (fixes R11's two serial
//             RTs per attempt) -> verify 128 tags == t (plugs the no-drain
//             visibility hole; rare retry since flag+data issued
//             back-to-back and poll+load adds >=2 RTs of slack) -> v_perm
//             repack (validated in R11) -> MFMA.
// R11 post-mortem: 2 serial vmcnt(0) per attempt x ~2 attempts x ~2000cy
// system-RT = its 8700cy/step. This round: poll(1RT) + load(1RT) + compute;
// producer drain RT removed. Worst case = R4-ish + rare retries, never hung.
// hbuf (both u32 buffers) + flags memset to 0 (tag 0 < any live tag).
// t=0 synthesizes h_0 = 0 in registers.
// ---------------------------------------------------------------------------

typedef short short8 __attribute__((ext_vector_type(8)));
typedef float f32x4 __attribute__((ext_vector_type(4)));
typedef int int4v __attribute__((ext_vector_type(4)));

#define NB 128
#define NT 512
#define ND 512
#define NH 512
#define NG 1536  // 3H

__device__ __forceinline__ unsigned short f2bf(float f) {
  union { float f; unsigned u; } v; v.f = f;
  unsigned r = v.u + 0x7fffu + ((v.u >> 16) & 1u);  // RNE
  return (unsigned short)(r >> 16);
}
__device__ __forceinline__ float bf2f(unsigned short u) {
  union { unsigned u; float f; } v; v.u = ((unsigned)u) << 16; return v.f;
}
__device__ __forceinline__ float sigmoid_f(float x) {
  float e = __builtin_amdgcn_exp2f(-1.4426950408889634f * x);
  return __builtin_amdgcn_rcpf(1.0f + e);
}
__device__ __forceinline__ float tanh_f(float x) {
  float e = __builtin_amdgcn_exp2f(2.8853900817779268f * x);
  return 1.0f - 2.0f * __builtin_amdgcn_rcpf(1.0f + e);
}
__device__ __forceinline__ short8 pack8(float4 a, float4 b) {
  short8 s;
  s[0] = (short)f2bf(a.x); s[1] = (short)f2bf(a.y);
  s[2] = (short)f2bf(a.z); s[3] = (short)f2bf(a.w);
  s[4] = (short)f2bf(b.x); s[5] = (short)f2bf(b.y);
  s[6] = (short)f2bf(b.z); s[7] = (short)f2bf(b.w);
  return s;
}

// 32 coherent dwordx4 loads (all 16 chunks: byte kk*128 and kk*128+16) with
// ONE vmcnt(0). p = lane pointer (u32*), already includes +q*8.
__device__ __forceinline__ void load_t32(const unsigned* p, int4v a[32]) {
  asm volatile(
      "global_load_dwordx4 %0,  %32, off sc0 sc1\n\t"
      "global_load_dwordx4 %1,  %32, off offset:16 sc0 sc1\n\t"
      "global_load_dwordx4 %2,  %32, off offset:128 sc0 sc1\n\t"
      "global_load_dwordx4 %3,  %32, off offset:144 sc0 sc1\n\t"
      "global_load_dwordx4 %4,  %32, off offset:256 sc0 sc1\n\t"
      "global_load_dwordx4 %5,  %32, off offset:272 sc0 sc1\n\t"
      "global_load_dwordx4 %6,  %32, off offset:384 sc0 sc1\n\t"
      "global_load_dwordx4 %7,  %32, off offset:400 sc0 sc1\n\t"
      "global_load_dwordx4 %8,  %32, off offset:512 sc0 sc1\n\t"
      "global_load_dwordx4 %9,  %32, off offset:528 sc0 sc1\n\t"
      "global_load_dwordx4 %10, %32, off offset:640 sc0 sc1\n\t"
      "global_load_dwordx4 %11, %32, off offset:656 sc0 sc1\n\t"
      "global_load_dwordx4 %12, %32, off offset:768 sc0 sc1\n\t"
      "global_load_dwordx4 %13, %32, off offset:784 sc0 sc1\n\t"
      "global_load_dwordx4 %14, %32, off offset:896 sc0 sc1\n\t"
      "global_load_dwordx4 %15, %32, off offset:912 sc0 sc1\n\t"
      "global_load_dwordx4 %16, %32, off offset:1024 sc0 sc1\n\t"
      "global_load_dwordx4 %17, %32, off offset:1040 sc0 sc1\n\t"
      "global_load_dwordx4 %18, %32, off offset:1152 sc0 sc1\n\t"
      "global_load_dwordx4 %19, %32, off offset:1168 sc0 sc1\n\t"
      "global_load_dwordx4 %20, %32, off offset:1280 sc0 sc1\n\t"
      "global_load_dwordx4 %21, %32, off offset:1296 sc0 sc1\n\t"
      "global_load_dwordx4 %22, %32, off offset:1408 sc0 sc1\n\t"
      "global_load_dwordx4 %23, %32, off offset:1424 sc0 sc1\n\t"
      "global_load_dwordx4 %24, %32, off offset:1536 sc0 sc1\n\t"
      "global_load_dwordx4 %25, %32, off offset:1552 sc0 sc1\n\t"
      "global_load_dwordx4 %26, %32, off offset:1664 sc0 sc1\n\t"
      "global_load_dwordx4 %27, %32, off offset:1680 sc0 sc1\n\t"
      "global_load_dwordx4 %28, %32, off offset:1792 sc0 sc1\n\t"
      "global_load_dwordx4 %29, %32, off offset:1808 sc0 sc1\n\t"
      "global_load_dwordx4 %30, %32, off offset:1920 sc0 sc1\n\t"
      "global_load_dwordx4 %31, %32, off offset:1936 sc0 sc1\n\t"
      "s_waitcnt vmcnt(0)"
      : "=&v"(a[0]), "=&v"(a[1]), "=&v"(a[2]), "=&v"(a[3]),
        "=&v"(a[4]), "=&v"(a[5]), "=&v"(a[6]), "=&v"(a[7]),
        "=&v"(a[8]), "=&v"(a[9]), "=&v"(a[10]), "=&v"(a[11]),
        "=&v"(a[12]), "=&v"(a[13]), "=&v"(a[14]), "=&v"(a[15]),
        "=&v"(a[16]), "=&v"(a[17]), "=&v"(a[18]), "=&v"(a[19]),
        "=&v"(a[20]), "=&v"(a[21]), "=&v"(a[22]), "=&v"(a[23]),
        "=&v"(a[24]), "=&v"(a[25]), "=&v"(a[26]), "=&v"(a[27]),
        "=&v"(a[28]), "=&v"(a[29]), "=&v"(a[30]), "=&v"(a[31])
      : "v"(p)
      : "memory");
}

// 4 tagged dword stores (rows erow..erow+3, stride 2048B), base pre-offset
// by +2 rows so 13-bit signed offsets reach all 4. NO drain.
__device__ __forceinline__ void store_t4(unsigned* p2, unsigned v0,
                                         unsigned v1, unsigned v2, unsigned v3) {
  asm volatile(
      "global_store_dword %0, %1, off offset:-4096 sc0 sc1\n\t"
      "global_store_dword %0, %2, off offset:-2048 sc0 sc1\n\t"
      "global_store_dword %0, %3, off sc0 sc1\n\t"
      "global_store_dword %0, %4, off offset:2048 sc0 sc1"
      :
      : "v"(p2), "v"(v0), "v"(v1), "v"(v2), "v"(v3)
      : "memory");
}

__device__ __forceinline__ unsigned poll_load(const unsigned* p) {
  unsigned f;
  asm volatile(
      "global_load_dword %0, %1, off sc0 sc1\n\t"
      "s_waitcnt vmcnt(0)"
      : "=v"(f) : "v"(p) : "memory");
  return f;
}

__device__ __forceinline__ void flag_store(unsigned* p, unsigned v) {
  asm volatile("global_store_dword %0, %1, off sc0 sc1"
               :: "v"(p), "v"(v) : "memory");
}

// ---------------------------------------------------------------------------
// IG = x @ Wih^T + bias, bf16 out. M=65536, N=1536, K=512. (unchanged)
// ---------------------------------------------------------------------------
__global__ __launch_bounds__(256) void ig_gemm(
    const float* __restrict__ x, const float* __restrict__ Wih,
    const float* __restrict__ bias, unsigned short* __restrict__ IG) {
  __shared__ unsigned short As[128 * 40];
  __shared__ unsigned short Bs[128 * 40];
  const int tid = threadIdx.x;
  const int bm = blockIdx.x, bn = blockIdx.y;
  const int lane = tid & 63, w = tid >> 6;
  const int wm = w >> 1, wn = w & 1;
  const int l15 = lane & 15, q = lane >> 4;

  f32x4 acc[4][4] = {};

  for (int kt = 0; kt < 16; ++kt) {
    __syncthreads();
#pragma unroll
    for (int j = 0; j < 4; ++j) {
      int fi = tid + 256 * j;
      int row = fi >> 3, kq = fi & 7;
      float4 v = *(const float4*)(x + (size_t)(bm * 128 + row) * ND + kt * 32 + kq * 4);
      ushort4 s = {f2bf(v.x), f2bf(v.y), f2bf(v.z), f2bf(v.w)};
      *(ushort4*)&As[row * 40 + kq * 4] = s;
    }
#pragma unroll
    for (int j = 0; j < 4; ++j) {
      int fi = tid + 256 * j;
      int row = fi >> 3, kq = fi & 7;
      float4 v = *(const float4*)(Wih + (size_t)(bn * 128 + row) * ND + kt * 32 + kq * 4);
      ushort4 s = {f2bf(v.x), f2bf(v.y), f2bf(v.z), f2bf(v.w)};
      *(ushort4*)&Bs[row * 40 + kq * 4] = s;
    }
    __syncthreads();

    short8 af[4], bfv[4];
#pragma unroll
    for (int tm = 0; tm < 4; ++tm)
      af[tm] = *(const short8*)&As[(wm * 64 + tm * 16 + l15) * 40 + q * 8];
#pragma unroll
    for (int tn = 0; tn < 4; ++tn)
      bfv[tn] = *(const short8*)&Bs[(wn * 64 + tn * 16 + l15) * 40 + q * 8];
#pragma unroll
    for (int tm = 0; tm < 4; ++tm)
#pragma unroll
      for (int tn = 0; tn < 4; ++tn)
        acc[tm][tn] = __builtin_amdgcn_mfma_f32_16x16x32_bf16(af[tm], bfv[tn], acc[tm][tn], 0, 0, 0);
  }

#pragma unroll
  for (int tm = 0; tm < 4; ++tm) {
#pragma unroll
    for (int tn = 0; tn < 4; ++tn) {
      int col = bn * 128 + wn * 64 + tn * 16 + l15;
      float bb = bias[col];
#pragma unroll
      for (int i = 0; i < 4; ++i) {
        int row = bm * 128 + wm * 64 + tm * 16 + q * 4 + i;
        IG[(size_t)row * NG + col] = f2bf(acc[tm][tn][i] + bb);
      }
    }
  }
}

// ---------------------------------------------------------------------------
// Persistent GRU recurrence. 64 blocks x 256 threads. (R4 topology)
// block = (group g of 32 batch rows, chunk c of 32 h-cols).
// wave (wm,wn): rows [b0+wm*16, +16), cols [c*32+wn*16, +16).
// h buffers: u32 tagged words (bf16<<16 | step). flags as in R4 (no drain
// before them; tags carry the data-visibility proof).
// ---------------------------------------------------------------------------
template <bool USE_IG>
__global__ __launch_bounds__(256, 1) void gru_rec(
    const float* __restrict__ x, const float* __restrict__ Wih,
    const float* __restrict__ Whh, const float* __restrict__ bias,
    const float* __restrict__ bn, const unsigned short* __restrict__ IG,
    unsigned* __restrict__ hbuf, unsigned* __restrict__ flags,
    float* __restrict__ hfin) {
  const int tid = threadIdx.x;
  const int lane = tid & 63;
  const int w = tid >> 6;
  const int wm = w >> 1, wn = w & 1;
  const int l15 = lane & 15, q = lane >> 4;
  const int g = blockIdx.x >> 4;   // 4 groups
  const int c = blockIdx.x & 15;   // 16 col-chunks of 32
  const int b0 = g * 32;
  const int col = c * 32 + wn * 16 + l15;  // this lane's h column
  const int mrow = b0 + wm * 16 + l15;     // A-fragment batch row
  const int erow = b0 + wm * 16 + q * 4;   // C-layout batch row base

  unsigned* const myflag = flags + ((g * 2 + wm) * 16 + c) * 2 + wn;
  const unsigned* const pollbase = flags + (g * 2 + wm) * 32;  // 32 flags

  // Whh B-fragments -> registers: 3 gates x 16 k-chunks (192 VGPRs)
  short8 bfr[3][16];
#pragma unroll
  for (int gt = 0; gt < 3; ++gt) {
    const float* src = Whh + (size_t)(gt * NH + col) * NH + q * 8;
#pragma unroll
    for (int kk = 0; kk < 16; ++kk) {
      float4 v0 = *(const float4*)(src + kk * 32);
      float4 v1 = *(const float4*)(src + kk * 32 + 4);
      bfr[gt][kk] = pack8(v0, v1);
    }
  }

  float bi_r = 0.f, bi_z = 0.f, bi_n = 0.f;
  if (!USE_IG) {
    bi_r = bias[col];
    bi_z = bias[NH + col];
    bi_n = bias[2 * NH + col];
  }
  const float bnv = bn[col];

  float hreg[4] = {0.f, 0.f, 0.f, 0.f};

  unsigned* const hb0 = hbuf;
  unsigned* const hb1 = hbuf + NB * NH;

  for (int t = 0; t < NT; ++t) {
    const unsigned* hcur = (t & 1) ? hb1 : hb0;
    unsigned* hnxt = (t & 1) ? hb0 : hb1;

    int4v a[32];
    if (t > 0) {
      // 1) cheap flag gate (R4 poll). First poll's vmcnt(0) also absorbs my
      //    own outstanding tagged stores + flag store (overlapped drain).
      if (lane < 32) {
        const unsigned* fp = pollbase + lane;
        unsigned f = poll_load(fp);
        while ((int)f < t) f = poll_load(fp);
      }
      // 2) one-RT tagged load + verify; retry rare (flag/data issued
      //    back-to-back, poll+load >= 2 RTs of slack).
      const unsigned* hp = hcur + (size_t)mrow * NH + q * 8;
      const unsigned tt = (unsigned)t;
      unsigned bad;
      do {
        load_t32(hp, a);
        bad = 0;
#pragma unroll
        for (int i = 0; i < 32; ++i) {
#pragma unroll
          for (int j = 0; j < 4; ++j)
            bad |= ((unsigned)a[i][j] ^ tt) & 0xffffu;
        }
      } while (__builtin_expect(bad != 0, 0));
    } else {
#pragma unroll
      for (int i = 0; i < 32; ++i) a[i] = (int4v){0, 0, 0, 0};
    }

    // IG loads (plain cached), after verify; hide under pack+MFMA.
    float igr[4], igz[4], ignv[4];
    if (USE_IG) {
#pragma unroll
      for (int i = 0; i < 4; ++i) {
        const size_t base = ((size_t)(erow + i) * NT + t) * NG + col;
        igr[i] = bf2f(IG[base]);
        igz[i] = bf2f(IG[base + NH]);
        ignv[i] = bf2f(IG[base + 2 * NH]);
      }
    }

    f32x4 ar = {0.f, 0.f, 0.f, 0.f};
    f32x4 az = {0.f, 0.f, 0.f, 0.f};
    f32x4 an = {0.f, 0.f, 0.f, 0.f};
    f32x4 ai = {0.f, 0.f, 0.f, 0.f};
#pragma unroll
    for (int kk = 0; kk < 16; ++kk) {
      // repack tagged dwords (value in hi16) -> bf16 short8 fragment
      const int4v dlo = a[2 * kk];
      const int4v dhi = a[2 * kk + 1];
      unsigned w0 = __builtin_amdgcn_perm((unsigned)dlo[1], (unsigned)dlo[0], 0x07060302u);
      unsigned w1 = __builtin_amdgcn_perm((unsigned)dlo[3], (unsigned)dlo[2], 0x07060302u);
      unsigned w2 = __builtin_amdgcn_perm((unsigned)dhi[1], (unsigned)dhi[0], 0x07060302u);
      unsigned w3 = __builtin_amdgcn_perm((unsigned)dhi[3], (unsigned)dhi[2], 0x07060302u);
      int4v wv = {(int)w0, (int)w1, (int)w2, (int)w3};
      short8 afk = __builtin_bit_cast(short8, wv);

      ar = __builtin_amdgcn_mfma_f32_16x16x32_bf16(afk, bfr[0][kk], ar, 0, 0, 0);
      az = __builtin_amdgcn_mfma_f32_16x16x32_bf16(afk, bfr[1][kk], az, 0, 0, 0);
      an = __builtin_amdgcn_mfma_f32_16x16x32_bf16(afk, bfr[2][kk], an, 0, 0, 0);
      if (!USE_IG) {
        const float* xp = x + ((size_t)mrow * NT + t) * ND + kk * 32 + q * 8;
        short8 xa = pack8(*(const float4*)xp, *(const float4*)(xp + 4));
#pragma unroll
        for (int gt = 0; gt < 3; ++gt) {
          const float* wp = Wih + (size_t)(gt * NH + col) * ND + kk * 32 + q * 8;
          short8 wf = pack8(*(const float4*)wp, *(const float4*)(wp + 4));
          if (gt == 0) ar = __builtin_amdgcn_mfma_f32_16x16x32_bf16(xa, wf, ar, 0, 0, 0);
          if (gt == 1) az = __builtin_amdgcn_mfma_f32_16x16x32_bf16(xa, wf, az, 0, 0, 0);
          if (gt == 2) ai = __builtin_amdgcn_mfma_f32_16x16x32_bf16(xa, wf, ai, 0, 0, 0);
        }
      }
    }

    // gates + h update; tagged stores (no drain) then flag (no drain)
    unsigned sv[4];
#pragma unroll
    for (int i = 0; i < 4; ++i) {
      float xr = USE_IG ? (ar[i] + igr[i]) : (ar[i] + bi_r);
      float xz = USE_IG ? (az[i] + igz[i]) : (az[i] + bi_z);
      float xin = USE_IG ? ignv[i] : (ai[i] + bi_n);
      float r = sigmoid_f(xr);
      float z = sigmoid_f(xz);
      float n = tanh_f(xin + r * (an[i] + bnv));
      float hn2 = (1.f - z) * n + z * hreg[i];
      hreg[i] = hn2;
      sv[i] = ((unsigned)f2bf(hn2) << 16) | (unsigned)(t + 1);
      if (t == NT - 1) hfin[(size_t)(erow + i) * NH + col] = hn2;
    }
    if (t != NT - 1) {
      unsigned* sp2 = hnxt + (size_t)(erow + 2) * NH + col;  // +2-row base
      store_t4(sp2, sv[0], sv[1], sv[2], sv[3]);
      if (lane == 0) flag_store(myflag, (unsigned)(t + 1));
    }
  }
}

// ---------------------------------------------------------------------------
// out = h_T @ Wlin^T + blin; mu = cols [0,256), logvar = cols [256,512).
// ---------------------------------------------------------------------------
__global__ __launch_bounds__(256) void final_linear(
    const float* __restrict__ hfin, const float* __restrict__ Wlin,
    const float* __restrict__ blin, float* __restrict__ out) {
  __shared__ float sh[16 * 516];
  const int tid = threadIdx.x;
  const int b0 = blockIdx.y * 16, o0 = blockIdx.x * 16;

  for (int j = tid; j < 16 * 128; j += 256) {
    int row = j >> 7, kq = j & 127;
    *(float4*)&sh[row * 516 + kq * 4] =
        *(const float4*)(hfin + (size_t)(b0 + row) * NH + kq * 4);
  }
  __syncthreads();

  const int bi = tid & 15, oi = tid >> 4;
  const int o = o0 + oi;
  const float4* wp = (const float4*)(Wlin + (size_t)o * NH);
  float4 a4 = {0.f, 0.f, 0.f, 0.f};
  for (int k4 = 0; k4 < 128; ++k4) {
    float4 wv = wp[k4];
    float4 hv = *(const float4*)&sh[bi * 516 + k4 * 4];
    a4.x += wv.x * hv.x; a4.y += wv.y * hv.y;
    a4.z += wv.z * hv.z; a4.w += wv.w * hv.w;
  }
  float v = a4.x + a4.y + a4.z + a4.w + blin[o];
  int b = b0 + bi;
  if (o < 256) out[b * 256 + o] = v;
  else out[32768 + b * 256 + (o - 256)] = v;
}

// ---------------------------------------------------------------------------
extern "C" void kernel_launch(void* const* d_in, const int* in_sizes, int n_in,
                              void* d_out, int out_size, void* d_ws, size_t ws_size,
                              hipStream_t stream) {
  const float* x    = (const float*)d_in[0];
  const float* Wih  = (const float*)d_in[1];
  const float* Whh  = (const float*)d_in[2];
  const float* bias = (const float*)d_in[3];
  const float* bn   = (const float*)d_in[4];
  const float* Wlin = (const float*)d_in[5];
  const float* blin = (const float*)d_in[6];
  float* out = (float*)d_out;

  char* ws = (char*)d_ws;
  // layout: [hbuf u32 x2 524288][flags 1024][hfin 262144][IG 201326592]
  unsigned* hbuf     = (unsigned*)ws;
  unsigned* flags    = (unsigned*)(ws + 524288);
  float* hfin        = (float*)(ws + 525312);
  unsigned short* IG = (unsigned short*)(ws + 787456);
  const size_t need_min = 787456;
  const size_t need_ig  = 787456 + (size_t)NB * NT * NG * 2;  // ~203 MB
  if (ws_size < need_min) return;

  // zero tagged h buffers + flags (tag/flag 0 < any live value)
  hipMemsetAsync(ws, 0, 525312, stream);

  const bool useIG = (ws_size >= need_ig);
  if (useIG) {
    ig_gemm<<<dim3(512, 12), 256, 0, stream>>>(x, Wih, bias, IG);
    gru_rec<true><<<64, 256, 0, stream>>>(x, Wih, Whh, bias, bn, IG, hbuf, flags, hfin);
  } else {
    gru_rec<false><<<64, 256, 0, stream>>>(x, Wih, Whh, bias, bn, nullptr, hbuf, flags, hfin);
  }
  final_linear<<<dim3(32, 8), 256, 0, stream>>>(hfin, Wlin, blin, out);
}

// Round 9
// 2704.039 us; speedup vs baseline: 2.1441x; 1.5171x over previous
//
#include <hip/hip_runtime.h>
#include <stdint.h>

// ---------------------------------------------------------------------------
// GRU encoder (B=128,T=512,D=512,H=512,L=256), MI355X gfx950.
//
// R13: TRAFFIC-MINIMIZED tagged-data recurrence.
// Topology: 8 groups x 16 batch rows; 4 blocks/group; 512-thread blocks
// (8 waves x 16 cols = 128 cols/block). Per step:
//   - one COOPERATIVE coherent load per block of the group's h_t
//     (16x512 tagged u32; 64B/thread = 4 dwordx4 + single vmcnt(0)),
//     per-thread tag verify (16 tags == t) with per-thread 64B retry,
//   - stage bf16 values into double-buffered LDS tile [16][520],
//   - __syncthreads, waves read A-fragments from LDS, 48 MFMA + gates,
//   - 4 tagged u32 stores (sc0 sc1), NO drain / NO flag / NO poll.
// Why: R4..R12 counters show the ring is bounded by coherent fabric traffic
// (4MB/step of sc0sc1 h re-reads: 16x block fan-out x 2x wave duplication)
// plus serial RTs. This cuts coherent reads 8x (512KB/step) and removes the
// drain+flag+poll RTs (the tagged load IS the sync). R12's spill bomb
// (128-VGPR asm block) is avoided: staging regs = 16/thread.
// Safety: tag-verify of h_t ⟹ all waves stored h_t ⟹ all finished reading
// h_{t-1} (loads retire before stores issue) ⟹ double-buffer overwrite and
// barrier phase-mixing are both impossible. Deadlock-free: stores are
// unconditional; retries terminate once stores land at the coherence point.
// hbuf (both u32 buffers) memset 0 (tag 0 < any live tag 1..511).
// t=0: h_0 = 0 synthesized (no load, no LDS, MFMA skipped).
// ---------------------------------------------------------------------------

typedef short short8 __attribute__((ext_vector_type(8)));
typedef float f32x4 __attribute__((ext_vector_type(4)));
typedef int int4v __attribute__((ext_vector_type(4)));

#define NB 128
#define NT 512
#define ND 512
#define NH 512
#define NG 1536  // 3H

__device__ __forceinline__ unsigned short f2bf(float f) {
  union { float f; unsigned u; } v; v.f = f;
  unsigned r = v.u + 0x7fffu + ((v.u >> 16) & 1u);  // RNE
  return (unsigned short)(r >> 16);
}
__device__ __forceinline__ float bf2f(unsigned short u) {
  union { unsigned u; float f; } v; v.u = ((unsigned)u) << 16; return v.f;
}
__device__ __forceinline__ float sigmoid_f(float x) {
  float e = __builtin_amdgcn_exp2f(-1.4426950408889634f * x);
  return __builtin_amdgcn_rcpf(1.0f + e);
}
__device__ __forceinline__ float tanh_f(float x) {
  float e = __builtin_amdgcn_exp2f(2.8853900817779268f * x);
  return 1.0f - 2.0f * __builtin_amdgcn_rcpf(1.0f + e);
}
__device__ __forceinline__ short8 pack8(float4 a, float4 b) {
  short8 s;
  s[0] = (short)f2bf(a.x); s[1] = (short)f2bf(a.y);
  s[2] = (short)f2bf(a.z); s[3] = (short)f2bf(a.w);
  s[4] = (short)f2bf(b.x); s[5] = (short)f2bf(b.y);
  s[6] = (short)f2bf(b.z); s[7] = (short)f2bf(b.w);
  return s;
}

// 4 coherent dwordx4 loads (this thread's 16 tagged words) + one drain.
__device__ __forceinline__ void load_t16(const unsigned* p, int4v a[4]) {
  asm volatile(
      "global_load_dwordx4 %0, %4, off sc0 sc1\n\t"
      "global_load_dwordx4 %1, %4, off offset:16 sc0 sc1\n\t"
      "global_load_dwordx4 %2, %4, off offset:32 sc0 sc1\n\t"
      "global_load_dwordx4 %3, %4, off offset:48 sc0 sc1\n\t"
      "s_waitcnt vmcnt(0)"
      : "=&v"(a[0]), "=&v"(a[1]), "=&v"(a[2]), "=&v"(a[3])
      : "v"(p)
      : "memory");
}

// 4 tagged dword stores (rows erow..erow+3, row stride 512*4B = 2048B),
// base pre-offset by +2 rows so 13-bit signed offsets reach all 4. NO drain.
__device__ __forceinline__ void store_t4(unsigned* p2, unsigned v0,
                                         unsigned v1, unsigned v2, unsigned v3) {
  asm volatile(
      "global_store_dword %0, %1, off offset:-4096 sc0 sc1\n\t"
      "global_store_dword %0, %2, off offset:-2048 sc0 sc1\n\t"
      "global_store_dword %0, %3, off sc0 sc1\n\t"
      "global_store_dword %0, %4, off offset:2048 sc0 sc1"
      :
      : "v"(p2), "v"(v0), "v"(v1), "v"(v2), "v"(v3)
      : "memory");
}

// ---------------------------------------------------------------------------
// IG = x @ Wih^T + bias, bf16 out. M=65536, N=1536, K=512. (unchanged)
// ---------------------------------------------------------------------------
__global__ __launch_bounds__(256) void ig_gemm(
    const float* __restrict__ x, const float* __restrict__ Wih,
    const float* __restrict__ bias, unsigned short* __restrict__ IG) {
  __shared__ unsigned short As[128 * 40];
  __shared__ unsigned short Bs[128 * 40];
  const int tid = threadIdx.x;
  const int bm = blockIdx.x, bn = blockIdx.y;
  const int lane = tid & 63, w = tid >> 6;
  const int wm = w >> 1, wn = w & 1;
  const int l15 = lane & 15, q = lane >> 4;

  f32x4 acc[4][4] = {};

  for (int kt = 0; kt < 16; ++kt) {
    __syncthreads();
#pragma unroll
    for (int j = 0; j < 4; ++j) {
      int fi = tid + 256 * j;
      int row = fi >> 3, kq = fi & 7;
      float4 v = *(const float4*)(x + (size_t)(bm * 128 + row) * ND + kt * 32 + kq * 4);
      ushort4 s = {f2bf(v.x), f2bf(v.y), f2bf(v.z), f2bf(v.w)};
      *(ushort4*)&As[row * 40 + kq * 4] = s;
    }
#pragma unroll
    for (int j = 0; j < 4; ++j) {
      int fi = tid + 256 * j;
      int row = fi >> 3, kq = fi & 7;
      float4 v = *(const float4*)(Wih + (size_t)(bn * 128 + row) * ND + kt * 32 + kq * 4);
      ushort4 s = {f2bf(v.x), f2bf(v.y), f2bf(v.z), f2bf(v.w)};
      *(ushort4*)&Bs[row * 40 + kq * 4] = s;
    }
    __syncthreads();

    short8 af[4], bfv[4];
#pragma unroll
    for (int tm = 0; tm < 4; ++tm)
      af[tm] = *(const short8*)&As[(wm * 64 + tm * 16 + l15) * 40 + q * 8];
#pragma unroll
    for (int tn = 0; tn < 4; ++tn)
      bfv[tn] = *(const short8*)&Bs[(wn * 64 + tn * 16 + l15) * 40 + q * 8];
#pragma unroll
    for (int tm = 0; tm < 4; ++tm)
#pragma unroll
      for (int tn = 0; tn < 4; ++tn)
        acc[tm][tn] = __builtin_amdgcn_mfma_f32_16x16x32_bf16(af[tm], bfv[tn], acc[tm][tn], 0, 0, 0);
  }

#pragma unroll
  for (int tm = 0; tm < 4; ++tm) {
#pragma unroll
    for (int tn = 0; tn < 4; ++tn) {
      int col = bn * 128 + wn * 64 + tn * 16 + l15;
      float bb = bias[col];
#pragma unroll
      for (int i = 0; i < 4; ++i) {
        int row = bm * 128 + wm * 64 + tm * 16 + q * 4 + i;
        IG[(size_t)row * NG + col] = f2bf(acc[tm][tn][i] + bb);
      }
    }
  }
}

// ---------------------------------------------------------------------------
// Persistent GRU recurrence. 32 blocks x 512 threads.
// block = (group g = bid>>2 of 16 batch rows, col-block cb = bid&3 of 128).
// wave w (0..7): cols cb*128 + w*16 + l15; C rows erow = g*16 + q*4.
// Loader: thread -> (lrow = tid>>5, lc0 = (tid&31)*16): 16 tagged words.
// h buffers: u32 (bf16<<16 | step). No flags.
// ---------------------------------------------------------------------------
template <bool USE_IG>
__global__ __launch_bounds__(512, 2) void gru_rec(
    const float* __restrict__ x, const float* __restrict__ Wih,
    const float* __restrict__ Whh, const float* __restrict__ bias,
    const float* __restrict__ bn, const unsigned short* __restrict__ IG,
    unsigned* __restrict__ hbuf, float* __restrict__ hfin) {
  __shared__ unsigned short hA[2][16][520];  // +8 pad: 2-way-max LDS banks

  const int tid = threadIdx.x;
  const int lane = tid & 63;
  const int w = tid >> 6;               // wave 0..7
  const int l15 = lane & 15, q = lane >> 4;
  const int g = blockIdx.x >> 2;        // 8 groups of 16 rows
  const int cb = blockIdx.x & 3;        // 4 col-blocks of 128
  const int col = cb * 128 + w * 16 + l15;  // this lane's h column
  const int erow = g * 16 + q * 4;          // C-layout batch row base
  const int lrow = tid >> 5;                // loader row 0..15
  const int lc0 = (tid & 31) * 16;          // loader col base

  // Whh B-fragments -> registers: 3 gates x 16 k-chunks (192 VGPRs)
  short8 bfr[3][16];
#pragma unroll
  for (int gt = 0; gt < 3; ++gt) {
    const float* src = Whh + (size_t)(gt * NH + col) * NH + q * 8;
#pragma unroll
    for (int kk = 0; kk < 16; ++kk) {
      float4 v0 = *(const float4*)(src + kk * 32);
      float4 v1 = *(const float4*)(src + kk * 32 + 4);
      bfr[gt][kk] = pack8(v0, v1);
    }
  }

  float bi_r = 0.f, bi_z = 0.f, bi_n = 0.f;
  if (!USE_IG) {
    bi_r = bias[col];
    bi_z = bias[NH + col];
    bi_n = bias[2 * NH + col];
  }
  const float bnv = bn[col];

  float hreg[4] = {0.f, 0.f, 0.f, 0.f};

  unsigned* const hb0 = hbuf;
  unsigned* const hb1 = hbuf + NB * NH;

  for (int t = 0; t < NT; ++t) {
    const unsigned* hcur = (t & 1) ? hb1 : hb0;
    unsigned* hnxt = (t & 1) ? hb0 : hb1;

    if (t > 0) {
      // cooperative tagged load of group h_t: 16 words/thread, verify,
      // per-thread 64B retry until all 16 tags == t.
      const unsigned* hp = hcur + (size_t)(g * 16 + lrow) * NH + lc0;
      const unsigned tt = (unsigned)t;
      int4v a4[4];
      unsigned bad;
      do {
        load_t16(hp, a4);
        bad = 0;
#pragma unroll
        for (int i = 0; i < 4; ++i) {
#pragma unroll
          for (int j = 0; j < 4; ++j)
            bad |= ((unsigned)a4[i][j] ^ tt) & 0xffffu;
        }
      } while (__builtin_expect(bad != 0, 0));

      // extract bf16 (hi16) -> 8 packed u32 -> LDS (2x ds_write_b128)
      unsigned pk[8];
#pragma unroll
      for (int i = 0; i < 4; ++i) {
        pk[2 * i]     = __builtin_amdgcn_perm((unsigned)a4[i][1], (unsigned)a4[i][0], 0x07060302u);
        pk[2 * i + 1] = __builtin_amdgcn_perm((unsigned)a4[i][3], (unsigned)a4[i][2], 0x07060302u);
      }
      *(int4v*)&hA[t & 1][lrow][lc0]     = (int4v){(int)pk[0], (int)pk[1], (int)pk[2], (int)pk[3]};
      *(int4v*)&hA[t & 1][lrow][lc0 + 8] = (int4v){(int)pk[4], (int)pk[5], (int)pk[6], (int)pk[7]};

      __syncthreads();  // uniform (t is block-uniform); no phase mixing:
                        // reaching barrier t+1 requires verified h_{t+1},
                        // which requires every thread passed barrier t.
    }

    // IG loads (plain cached); latency hides under LDS reads + MFMA chain.
    float igr[4], igz[4], ignv[4];
    if (USE_IG) {
#pragma unroll
      for (int i = 0; i < 4; ++i) {
        const size_t base = ((size_t)(erow + i) * NT + t) * NG + col;
        igr[i] = bf2f(IG[base]);
        igz[i] = bf2f(IG[base + NH]);
        ignv[i] = bf2f(IG[base + 2 * NH]);
      }
    }

    f32x4 ar = {0.f, 0.f, 0.f, 0.f};
    f32x4 az = {0.f, 0.f, 0.f, 0.f};
    f32x4 an = {0.f, 0.f, 0.f, 0.f};
    f32x4 ai = {0.f, 0.f, 0.f, 0.f};
    if (t > 0) {
#pragma unroll
      for (int kk = 0; kk < 16; ++kk) {
        short8 afk = *(const short8*)&hA[t & 1][l15][kk * 32 + q * 8];
        ar = __builtin_amdgcn_mfma_f32_16x16x32_bf16(afk, bfr[0][kk], ar, 0, 0, 0);
        az = __builtin_amdgcn_mfma_f32_16x16x32_bf16(afk, bfr[1][kk], az, 0, 0, 0);
        an = __builtin_amdgcn_mfma_f32_16x16x32_bf16(afk, bfr[2][kk], an, 0, 0, 0);
      }
    }
    if (!USE_IG) {
#pragma unroll
      for (int kk = 0; kk < 16; ++kk) {
        const float* xp = x + ((size_t)(g * 16 + l15) * NT + t) * ND + kk * 32 + q * 8;
        short8 xa = pack8(*(const float4*)xp, *(const float4*)(xp + 4));
#pragma unroll
        for (int gt = 0; gt < 3; ++gt) {
          const float* wp = Wih + (size_t)(gt * NH + col) * ND + kk * 32 + q * 8;
          short8 wf = pack8(*(const float4*)wp, *(const float4*)(wp + 4));
          if (gt == 0) ar = __builtin_amdgcn_mfma_f32_16x16x32_bf16(xa, wf, ar, 0, 0, 0);
          if (gt == 1) az = __builtin_amdgcn_mfma_f32_16x16x32_bf16(xa, wf, az, 0, 0, 0);
          if (gt == 2) ai = __builtin_amdgcn_mfma_f32_16x16x32_bf16(xa, wf, ai, 0, 0, 0);
        }
      }
    }

    // gates + h update; publish tagged h_{t+1} (no drain, no flag)
    unsigned sv[4];
#pragma unroll
    for (int i = 0; i < 4; ++i) {
      float xr = USE_IG ? (ar[i] + igr[i]) : (ar[i] + bi_r);
      float xz = USE_IG ? (az[i] + igz[i]) : (az[i] + bi_z);
      float xin = USE_IG ? ignv[i] : (ai[i] + bi_n);
      float r = sigmoid_f(xr);
      float z = sigmoid_f(xz);
      float n = tanh_f(xin + r * (an[i] + bnv));
      float hn2 = (1.f - z) * n + z * hreg[i];
      hreg[i] = hn2;
      sv[i] = ((unsigned)f2bf(hn2) << 16) | (unsigned)(t + 1);
      if (t == NT - 1) hfin[(size_t)(erow + i) * NH + col] = hn2;
    }
    if (t != NT - 1) {
      unsigned* sp2 = hnxt + (size_t)(erow + 2) * NH + col;  // +2-row base
      store_t4(sp2, sv[0], sv[1], sv[2], sv[3]);
    }
  }
}

// ---------------------------------------------------------------------------
// out = h_T @ Wlin^T + blin; mu = cols [0,256), logvar = cols [256,512).
// ---------------------------------------------------------------------------
__global__ __launch_bounds__(256) void final_linear(
    const float* __restrict__ hfin, const float* __restrict__ Wlin,
    const float* __restrict__ blin, float* __restrict__ out) {
  __shared__ float sh[16 * 516];
  const int tid = threadIdx.x;
  const int b0 = blockIdx.y * 16, o0 = blockIdx.x * 16;

  for (int j = tid; j < 16 * 128; j += 256) {
    int row = j >> 7, kq = j & 127;
    *(float4*)&sh[row * 516 + kq * 4] =
        *(const float4*)(hfin + (size_t)(b0 + row) * NH + kq * 4);
  }
  __syncthreads();

  const int bi = tid & 15, oi = tid >> 4;
  const int o = o0 + oi;
  const float4* wp = (const float4*)(Wlin + (size_t)o * NH);
  float4 a4 = {0.f, 0.f, 0.f, 0.f};
  for (int k4 = 0; k4 < 128; ++k4) {
    float4 wv = wp[k4];
    float4 hv = *(const float4*)&sh[bi * 516 + k4 * 4];
    a4.x += wv.x * hv.x; a4.y += wv.y * hv.y;
    a4.z += wv.z * hv.z; a4.w += wv.w * hv.w;
  }
  float v = a4.x + a4.y + a4.z + a4.w + blin[o];
  int b = b0 + bi;
  if (o < 256) out[b * 256 + o] = v;
  else out[32768 + b * 256 + (o - 256)] = v;
}

// ---------------------------------------------------------------------------
extern "C" void kernel_launch(void* const* d_in, const int* in_sizes, int n_in,
                              void* d_out, int out_size, void* d_ws, size_t ws_size,
                              hipStream_t stream) {
  const float* x    = (const float*)d_in[0];
  const float* Wih  = (const float*)d_in[1];
  const float* Whh  = (const float*)d_in[2];
  const float* bias = (const float*)d_in[3];
  const float* bn   = (const float*)d_in[4];
  const float* Wlin = (const float*)d_in[5];
  const float* blin = (const float*)d_in[6];
  float* out = (float*)d_out;

  char* ws = (char*)d_ws;
  // layout: [hbuf u32 x2 524288][hfin 262144][IG 201326592]
  unsigned* hbuf     = (unsigned*)ws;
  float* hfin        = (float*)(ws + 524288);
  unsigned short* IG = (unsigned short*)(ws + 786432);
  const size_t need_min = 786432;
  const size_t need_ig  = 786432 + (size_t)NB * NT * NG * 2;  // ~203 MB
  if (ws_size < need_min) return;

  // zero both tagged h buffers (tag 0 < any live tag)
  hipMemsetAsync(ws, 0, 524288, stream);

  const bool useIG = (ws_size >= need_ig);
  if (useIG) {
    ig_gemm<<<dim3(512, 12), 256, 0, stream>>>(x, Wih, bias, IG);
    gru_rec<true><<<32, 512, 0, stream>>>(x, Wih, Whh, bias, bn, IG, hbuf, hfin);
  } else {
    gru_rec<false><<<32, 512, 0, stream>>>(x, Wih, Whh, bias, bn, nullptr, hbuf, hfin);
  }
  final_linear<<<dim3(32, 8), 256, 0, stream>>>(hfin, Wlin, blin, out);
}

// Round 10
// 2268.324 us; speedup vs baseline: 2.5560x; 1.1921x over previous
//
#include <hip/hip_runtime.h>
#include <stdint.h>

// ---------------------------------------------------------------------------
// GRU encoder (B=128,T=512,D=512,H=512,L=256), MI355X gfx950.
//
// R14: R4-EXACT protocol (drain-then-flag, poll-then-load, proven 2008us
// gru_rec) with ONE change: all sync memops at DEVICE scope (sc1) instead of
// SYSTEM (sc0 sc1). Evidence: R4's WRITE_SIZE == h volume proves system
// scope writes every h store through to HBM and acks from there; device
// scope stops at the IF$/MALL coherence point (shorter ack + fill RTs).
// R7 attempted sc1-only but the container died before the bench ran — never
// measured. This round adds the R10 safety harness: the flag poll escalates
// to the proven system-scope poll after 8 device-scope tries, so a stale
// flag is SLOW, never a hang; stale data would fail absmax visibly.
// Protocol-variant history (R6/R9-R13): flag-late, agent fences, tagged
// data, LDS-staged coop loads all regressed — R4's 3-RT protocol stands;
// this attacks RT LATENCY, not RT count.
// Kept from verified rounds: h_0 synthesized in registers (no hbuf memset),
// flags-only memset.
// ---------------------------------------------------------------------------

typedef short short8 __attribute__((ext_vector_type(8)));
typedef float f32x4 __attribute__((ext_vector_type(4)));
typedef int int4v __attribute__((ext_vector_type(4)));

#define NB 128
#define NT 512
#define ND 512
#define NH 512
#define NG 1536  // 3H

__device__ __forceinline__ unsigned short f2bf(float f) {
  union { float f; unsigned u; } v; v.f = f;
  unsigned r = v.u + 0x7fffu + ((v.u >> 16) & 1u);  // RNE
  return (unsigned short)(r >> 16);
}
__device__ __forceinline__ float bf2f(unsigned short u) {
  union { unsigned u; float f; } v; v.u = ((unsigned)u) << 16; return v.f;
}
__device__ __forceinline__ float sigmoid_f(float x) {
  float e = __builtin_amdgcn_exp2f(-1.4426950408889634f * x);
  return __builtin_amdgcn_rcpf(1.0f + e);
}
__device__ __forceinline__ float tanh_f(float x) {
  float e = __builtin_amdgcn_exp2f(2.8853900817779268f * x);
  return 1.0f - 2.0f * __builtin_amdgcn_rcpf(1.0f + e);
}
__device__ __forceinline__ short8 pack8(float4 a, float4 b) {
  short8 s;
  s[0] = (short)f2bf(a.x); s[1] = (short)f2bf(a.y);
  s[2] = (short)f2bf(a.z); s[3] = (short)f2bf(a.w);
  s[4] = (short)f2bf(b.x); s[5] = (short)f2bf(b.y);
  s[6] = (short)f2bf(b.z); s[7] = (short)f2bf(b.w);
  return s;
}

// 16 device-scope 16B loads (this lane's A-fragments for K=512) + one drain.
// p must already include the per-quad `+ q*8` element offset.
__device__ __forceinline__ void load_h16(const unsigned short* p, int4v a[16]) {
  asm volatile(
      "global_load_dwordx4 %0,  %16, off sc1\n\t"
      "global_load_dwordx4 %1,  %16, off offset:64 sc1\n\t"
      "global_load_dwordx4 %2,  %16, off offset:128 sc1\n\t"
      "global_load_dwordx4 %3,  %16, off offset:192 sc1\n\t"
      "global_load_dwordx4 %4,  %16, off offset:256 sc1\n\t"
      "global_load_dwordx4 %5,  %16, off offset:320 sc1\n\t"
      "global_load_dwordx4 %6,  %16, off offset:384 sc1\n\t"
      "global_load_dwordx4 %7,  %16, off offset:448 sc1\n\t"
      "global_load_dwordx4 %8,  %16, off offset:512 sc1\n\t"
      "global_load_dwordx4 %9,  %16, off offset:576 sc1\n\t"
      "global_load_dwordx4 %10, %16, off offset:640 sc1\n\t"
      "global_load_dwordx4 %11, %16, off offset:704 sc1\n\t"
      "global_load_dwordx4 %12, %16, off offset:768 sc1\n\t"
      "global_load_dwordx4 %13, %16, off offset:832 sc1\n\t"
      "global_load_dwordx4 %14, %16, off offset:896 sc1\n\t"
      "global_load_dwordx4 %15, %16, off offset:960 sc1\n\t"
      "s_waitcnt vmcnt(0)"
      : "=&v"(a[0]), "=&v"(a[1]), "=&v"(a[2]), "=&v"(a[3]),
        "=&v"(a[4]), "=&v"(a[5]), "=&v"(a[6]), "=&v"(a[7]),
        "=&v"(a[8]), "=&v"(a[9]), "=&v"(a[10]), "=&v"(a[11]),
        "=&v"(a[12]), "=&v"(a[13]), "=&v"(a[14]), "=&v"(a[15])
      : "v"(p)
      : "memory");
}

// 4 device-scope short stores (rows erow..erow+3, stride NH*2=1024B) + drain
// so the subsequent flag store implies device-wide visibility of this slice.
__device__ __forceinline__ void store_h4(unsigned short* p, unsigned v0,
                                         unsigned v1, unsigned v2, unsigned v3) {
  asm volatile(
      "global_store_short %0, %1, off sc1\n\t"
      "global_store_short %0, %2, off offset:1024 sc1\n\t"
      "global_store_short %0, %3, off offset:2048 sc1\n\t"
      "global_store_short %0, %4, off offset:3072 sc1\n\t"
      "s_waitcnt vmcnt(0)"
      :
      : "v"(p), "v"(v0), "v"(v1), "v"(v2), "v"(v3)
      : "memory");
}

// device-scope poll
__device__ __forceinline__ unsigned poll_load_dev(const unsigned* p) {
  unsigned f;
  asm volatile(
      "global_load_dword %0, %1, off sc1\n\t"
      "s_waitcnt vmcnt(0)"
      : "=v"(f) : "v"(p) : "memory");
  return f;
}

// system-scope poll (R4-proven): escalation fallback, guaranteed fresh.
__device__ __forceinline__ unsigned poll_load_sys(const unsigned* p) {
  unsigned f;
  asm volatile(
      "global_load_dword %0, %1, off sc0 sc1\n\t"
      "s_waitcnt vmcnt(0)"
      : "=v"(f) : "v"(p) : "memory");
  return f;
}

__device__ __forceinline__ void flag_store(unsigned* p, unsigned v) {
  asm volatile("global_store_dword %0, %1, off sc1"
               :: "v"(p), "v"(v) : "memory");
}

// ---------------------------------------------------------------------------
// IG = x @ Wih^T + bias, bf16 out. M=65536, N=1536, K=512. (unchanged)
// ---------------------------------------------------------------------------
__global__ __launch_bounds__(256) void ig_gemm(
    const float* __restrict__ x, const float* __restrict__ Wih,
    const float* __restrict__ bias, unsigned short* __restrict__ IG) {
  __shared__ unsigned short As[128 * 40];
  __shared__ unsigned short Bs[128 * 40];
  const int tid = threadIdx.x;
  const int bm = blockIdx.x, bn = blockIdx.y;
  const int lane = tid & 63, w = tid >> 6;
  const int wm = w >> 1, wn = w & 1;
  const int l15 = lane & 15, q = lane >> 4;

  f32x4 acc[4][4] = {};

  for (int kt = 0; kt < 16; ++kt) {
    __syncthreads();
#pragma unroll
    for (int j = 0; j < 4; ++j) {
      int fi = tid + 256 * j;
      int row = fi >> 3, kq = fi & 7;
      float4 v = *(const float4*)(x + (size_t)(bm * 128 + row) * ND + kt * 32 + kq * 4);
      ushort4 s = {f2bf(v.x), f2bf(v.y), f2bf(v.z), f2bf(v.w)};
      *(ushort4*)&As[row * 40 + kq * 4] = s;
    }
#pragma unroll
    for (int j = 0; j < 4; ++j) {
      int fi = tid + 256 * j;
      int row = fi >> 3, kq = fi & 7;
      float4 v = *(const float4*)(Wih + (size_t)(bn * 128 + row) * ND + kt * 32 + kq * 4);
      ushort4 s = {f2bf(v.x), f2bf(v.y), f2bf(v.z), f2bf(v.w)};
      *(ushort4*)&Bs[row * 40 + kq * 4] = s;
    }
    __syncthreads();

    short8 af[4], bfv[4];
#pragma unroll
    for (int tm = 0; tm < 4; ++tm)
      af[tm] = *(const short8*)&As[(wm * 64 + tm * 16 + l15) * 40 + q * 8];
#pragma unroll
    for (int tn = 0; tn < 4; ++tn)
      bfv[tn] = *(const short8*)&Bs[(wn * 64 + tn * 16 + l15) * 40 + q * 8];
#pragma unroll
    for (int tm = 0; tm < 4; ++tm)
#pragma unroll
      for (int tn = 0; tn < 4; ++tn)
        acc[tm][tn] = __builtin_amdgcn_mfma_f32_16x16x32_bf16(af[tm], bfv[tn], acc[tm][tn], 0, 0, 0);
  }

#pragma unroll
  for (int tm = 0; tm < 4; ++tm) {
#pragma unroll
    for (int tn = 0; tn < 4; ++tn) {
      int col = bn * 128 + wn * 64 + tn * 16 + l15;
      float bb = bias[col];
#pragma unroll
      for (int i = 0; i < 4; ++i) {
        int row = bm * 128 + wm * 64 + tm * 16 + q * 4 + i;
        IG[(size_t)row * NG + col] = f2bf(acc[tm][tn][i] + bb);
      }
    }
  }
}

// ---------------------------------------------------------------------------
// Persistent GRU recurrence. 64 blocks x 256 threads. (R4 topology/protocol)
// block = (group g of 32 batch rows, chunk c of 32 h-cols).
// wave (wm,wn): rows [b0+wm*16, +16), cols [c*32+wn*16, +16).
// flags[((g*2+wm)*16+c)*2+wn] = step count written by that producer wave
// (h stores drained at device scope before the flag store).
// ---------------------------------------------------------------------------
template <bool USE_IG>
__global__ __launch_bounds__(256, 1) void gru_rec(
    const float* __restrict__ x, const float* __restrict__ Wih,
    const float* __restrict__ Whh, const float* __restrict__ bias,
    const float* __restrict__ bn, const unsigned short* __restrict__ IG,
    unsigned short* __restrict__ hbuf, unsigned* __restrict__ flags,
    float* __restrict__ hfin) {
  const int tid = threadIdx.x;
  const int lane = tid & 63;
  const int w = tid >> 6;
  const int wm = w >> 1, wn = w & 1;
  const int l15 = lane & 15, q = lane >> 4;
  const int g = blockIdx.x >> 4;   // 4 groups
  const int c = blockIdx.x & 15;   // 16 col-chunks of 32
  const int b0 = g * 32;
  const int col = c * 32 + wn * 16 + l15;  // this lane's h column
  const int mrow = b0 + wm * 16 + l15;     // A-fragment batch row
  const int erow = b0 + wm * 16 + q * 4;   // C-layout batch row base

  unsigned* const myflag = flags + ((g * 2 + wm) * 16 + c) * 2 + wn;
  const unsigned* const pollbase = flags + (g * 2 + wm) * 32;  // 32 flags

  // Whh B-fragments -> registers: 3 gates x 16 k-chunks (192 VGPRs)
  short8 bfr[3][16];
#pragma unroll
  for (int gt = 0; gt < 3; ++gt) {
    const float* src = Whh + (size_t)(gt * NH + col) * NH + q * 8;
#pragma unroll
    for (int kk = 0; kk < 16; ++kk) {
      float4 v0 = *(const float4*)(src + kk * 32);
      float4 v1 = *(const float4*)(src + kk * 32 + 4);
      bfr[gt][kk] = pack8(v0, v1);
    }
  }

  float bi_r = 0.f, bi_z = 0.f, bi_n = 0.f;
  if (!USE_IG) {
    bi_r = bias[col];
    bi_z = bias[NH + col];
    bi_n = bias[2 * NH + col];
  }
  const float bnv = bn[col];

  float hreg[4] = {0.f, 0.f, 0.f, 0.f};

  unsigned short* const hb0 = hbuf;
  unsigned short* const hb1 = hbuf + NB * NH;

  for (int t = 0; t < NT; ++t) {
    const unsigned short* hcur = (t & 1) ? hb1 : hb0;
    unsigned short* hnxt = (t & 1) ? hb0 : hb1;

    // IG loads first (plain cached loads; latency overlaps poll + h loads).
    float igr[4], igz[4], ign[4];
    if (USE_IG) {
#pragma unroll
      for (int i = 0; i < 4; ++i) {
        const size_t base = ((size_t)(erow + i) * NT + t) * NG + col;
        igr[i] = bf2f(IG[base]);
        igz[i] = bf2f(IG[base + NH]);
        ign[i] = bf2f(IG[base + 2 * NH]);
      }
    }

    int4v araw[16];
    if (t > 0) {
      // wait for the 32 producer waves of this row-half to have written h_t.
      // Device-scope poll; bounded escalation to system scope (cannot hang).
      if (lane < 32) {
        const unsigned* fp = pollbase + lane;
        unsigned f = poll_load_dev(fp);
        int tries = 0;
        while ((int)f < t) {
          if (++tries > 8) f = poll_load_sys(fp);
          else             f = poll_load_dev(fp);
        }
      }
      // implicit reconvergence: all lanes proceed after slowest poll
      // device-scope h_t A-fragments, full K=512 (per-quad +q*8 offset)
      load_h16(hcur + (size_t)mrow * NH + q * 8, araw);
    } else {
      // h_0 = 0: no poll, no load
#pragma unroll
      for (int kk = 0; kk < 16; ++kk) araw[kk] = (int4v){0, 0, 0, 0};
    }

    f32x4 ar = {0.f, 0.f, 0.f, 0.f};
    f32x4 az = {0.f, 0.f, 0.f, 0.f};
    f32x4 an = {0.f, 0.f, 0.f, 0.f};
    f32x4 ai = {0.f, 0.f, 0.f, 0.f};
#pragma unroll
    for (int kk = 0; kk < 16; ++kk) {
      short8 afk = __builtin_bit_cast(short8, araw[kk]);
      ar = __builtin_amdgcn_mfma_f32_16x16x32_bf16(afk, bfr[0][kk], ar, 0, 0, 0);
      az = __builtin_amdgcn_mfma_f32_16x16x32_bf16(afk, bfr[1][kk], az, 0, 0, 0);
      an = __builtin_amdgcn_mfma_f32_16x16x32_bf16(afk, bfr[2][kk], an, 0, 0, 0);
      if (!USE_IG) {
        const float* xp = x + ((size_t)mrow * NT + t) * ND + kk * 32 + q * 8;
        short8 xa = pack8(*(const float4*)xp, *(const float4*)(xp + 4));
#pragma unroll
        for (int gt = 0; gt < 3; ++gt) {
          const float* wp = Wih + (size_t)(gt * NH + col) * ND + kk * 32 + q * 8;
          short8 wf = pack8(*(const float4*)wp, *(const float4*)(wp + 4));
          if (gt == 0) ar = __builtin_amdgcn_mfma_f32_16x16x32_bf16(xa, wf, ar, 0, 0, 0);
          if (gt == 1) az = __builtin_amdgcn_mfma_f32_16x16x32_bf16(xa, wf, az, 0, 0, 0);
          if (gt == 2) ai = __builtin_amdgcn_mfma_f32_16x16x32_bf16(xa, wf, ai, 0, 0, 0);
        }
      }
    }

    // gates + h update; store via device-scope short stores, drain, flag
    unsigned sv[4];
#pragma unroll
    for (int i = 0; i < 4; ++i) {
      float xr = USE_IG ? (ar[i] + igr[i]) : (ar[i] + bi_r);
      float xz = USE_IG ? (az[i] + igz[i]) : (az[i] + bi_z);
      float xin = USE_IG ? ign[i] : (ai[i] + bi_n);
      float r = sigmoid_f(xr);
      float z = sigmoid_f(xz);
      float n = tanh_f(xin + r * (an[i] + bnv));
      float hn2 = (1.f - z) * n + z * hreg[i];
      hreg[i] = hn2;
      sv[i] = (unsigned)f2bf(hn2);
      if (t == NT - 1) hfin[(size_t)(erow + i) * NH + col] = hn2;
    }
    if (t != NT - 1) {
      store_h4(hnxt + (size_t)erow * NH + col, sv[0], sv[1], sv[2], sv[3]);
      if (lane == 0) flag_store(myflag, (unsigned)(t + 1));
    }
  }
}

// ---------------------------------------------------------------------------
// out = h_T @ Wlin^T + blin; mu = cols [0,256), logvar = cols [256,512).
// ---------------------------------------------------------------------------
__global__ __launch_bounds__(256) void final_linear(
    const float* __restrict__ hfin, const float* __restrict__ Wlin,
    const float* __restrict__ blin, float* __restrict__ out) {
  __shared__ float sh[16 * 516];
  const int tid = threadIdx.x;
  const int b0 = blockIdx.y * 16, o0 = blockIdx.x * 16;

  for (int j = tid; j < 16 * 128; j += 256) {
    int row = j >> 7, kq = j & 127;
    *(float4*)&sh[row * 516 + kq * 4] =
        *(const float4*)(hfin + (size_t)(b0 + row) * NH + kq * 4);
  }
  __syncthreads();

  const int bi = tid & 15, oi = tid >> 4;
  const int o = o0 + oi;
  const float4* wp = (const float4*)(Wlin + (size_t)o * NH);
  float4 a4 = {0.f, 0.f, 0.f, 0.f};
  for (int k4 = 0; k4 < 128; ++k4) {
    float4 wv = wp[k4];
    float4 hv = *(const float4*)&sh[bi * 516 + k4 * 4];
    a4.x += wv.x * hv.x; a4.y += wv.y * hv.y;
    a4.z += wv.z * hv.z; a4.w += wv.w * hv.w;
  }
  float v = a4.x + a4.y + a4.z + a4.w + blin[o];
  int b = b0 + bi;
  if (o < 256) out[b * 256 + o] = v;
  else out[32768 + b * 256 + (o - 256)] = v;
}

// ---------------------------------------------------------------------------
extern "C" void kernel_launch(void* const* d_in, const int* in_sizes, int n_in,
                              void* d_out, int out_size, void* d_ws, size_t ws_size,
                              hipStream_t stream) {
  const float* x    = (const float*)d_in[0];
  const float* Wih  = (const float*)d_in[1];
  const float* Whh  = (const float*)d_in[2];
  const float* bias = (const float*)d_in[3];
  const float* bn   = (const float*)d_in[4];
  const float* Wlin = (const float*)d_in[5];
  const float* blin = (const float*)d_in[6];
  float* out = (float*)d_out;

  char* ws = (char*)d_ws;
  // layout: [hbuf 262144][flags 1024][hfin 262144][IG 201326592]
  unsigned short* hbuf = (unsigned short*)ws;
  unsigned* flags      = (unsigned*)(ws + 262144);
  float* hfin          = (float*)(ws + 263168);
  unsigned short* IG   = (unsigned short*)(ws + 525312);
  const size_t need_min = 525312;
  const size_t need_ig  = 525312 + (size_t)NB * NT * NG * 2;  // ~203 MB
  if (ws_size < need_min) return;

  // zero flags only (h_0 is synthesized in registers; hbuf needs no init)
  hipMemsetAsync(ws + 262144, 0, 1024, stream);

  const bool useIG = (ws_size >= need_ig);
  if (useIG) {
    ig_gemm<<<dim3(512, 12), 256, 0, stream>>>(x, Wih, bias, IG);
    gru_rec<true><<<64, 256, 0, stream>>>(x, Wih, Whh, bias, bn, IG, hbuf, flags, hfin);
  } else {
    gru_rec<false><<<64, 256, 0, stream>>>(x, Wih, Whh, bias, bn, nullptr, hbuf, flags, hfin);
  }
  final_linear<<<dim3(32, 8), 256, 0, stream>>>(hfin, Wlin, blin, out);
}

// Round 11
// 2252.188 us; speedup vs baseline: 2.5743x; 1.0072x over previous
//
#include <hip/hip_runtime.h>
#include <stdint.h>

// ---------------------------------------------------------------------------
// GRU encoder (B=128,T=512,D=512,H=512,L=256), MI355X gfx950.
//
// R15: FUSED producer-consumer launch. R14 measured sc1 == sc0sc1 (WRITE_SIZE
// still == h volume): the R4 3-RT ring (~2000us) is the measured floor for
// this sync topology — 11 protocol variants tried, none beat it. Remaining
// structural waste: ig_gemm (~250us, whole GPU) SERIALIZES in front of a
// recurrence that uses only 64 blocks (~25% of CUs). This round fuses them:
// one 256-block launch; blocks 0..63 = exact R14 recurrence; blocks 64..255
// = persistent IG producers, tiles ordered quarter-major/b-major so early
// timesteps complete first (quarter 0 in ~80us, group 0's tiles in ~20us).
//   producer tile: gemm body -> sc0sc1 IG stores -> vmcnt(0) drain ->
//                  igflag[bm*12+bn]=1 (system scope).
//   consumer: at t%128==0 (4x/run) poll the 96 tile flags covering its
//             group's rows x 3 gate-columns BEFORE touching that quarter's
//             IG (first-touch-after-flag => plain cached IG loads stay
//             safe; IG has zero reuse so nothing is lost).
// Co-residency: 256 blocks @216 VGPR -> >=1 block/CU -> all resident at
// launch -> producers always run -> consumer flag-waits terminate. Producers
// exit after ~32 tiles. h-ring code byte-identical to R14 (passed, 2268us).
// ---------------------------------------------------------------------------

typedef short short8 __attribute__((ext_vector_type(8)));
typedef float f32x4 __attribute__((ext_vector_type(4)));
typedef int int4v __attribute__((ext_vector_type(4)));

#define NB 128
#define NT 512
#define ND 512
#define NH 512
#define NG 1536  // 3H

__device__ __forceinline__ unsigned short f2bf(float f) {
  union { float f; unsigned u; } v; v.f = f;
  unsigned r = v.u + 0x7fffu + ((v.u >> 16) & 1u);  // RNE
  return (unsigned short)(r >> 16);
}
__device__ __forceinline__ float bf2f(unsigned short u) {
  union { unsigned u; float f; } v; v.u = ((unsigned)u) << 16; return v.f;
}
__device__ __forceinline__ float sigmoid_f(float x) {
  float e = __builtin_amdgcn_exp2f(-1.4426950408889634f * x);
  return __builtin_amdgcn_rcpf(1.0f + e);
}
__device__ __forceinline__ float tanh_f(float x) {
  float e = __builtin_amdgcn_exp2f(2.8853900817779268f * x);
  return 1.0f - 2.0f * __builtin_amdgcn_rcpf(1.0f + e);
}
__device__ __forceinline__ short8 pack8(float4 a, float4 b) {
  short8 s;
  s[0] = (short)f2bf(a.x); s[1] = (short)f2bf(a.y);
  s[2] = (short)f2bf(a.z); s[3] = (short)f2bf(a.w);
  s[4] = (short)f2bf(b.x); s[5] = (short)f2bf(b.y);
  s[6] = (short)f2bf(b.z); s[7] = (short)f2bf(b.w);
  return s;
}

// 16 device-scope 16B loads (this lane's A-fragments for K=512) + one drain.
__device__ __forceinline__ void load_h16(const unsigned short* p, int4v a[16]) {
  asm volatile(
      "global_load_dwordx4 %0,  %16, off sc1\n\t"
      "global_load_dwordx4 %1,  %16, off offset:64 sc1\n\t"
      "global_load_dwordx4 %2,  %16, off offset:128 sc1\n\t"
      "global_load_dwordx4 %3,  %16, off offset:192 sc1\n\t"
      "global_load_dwordx4 %4,  %16, off offset:256 sc1\n\t"
      "global_load_dwordx4 %5,  %16, off offset:320 sc1\n\t"
      "global_load_dwordx4 %6,  %16, off offset:384 sc1\n\t"
      "global_load_dwordx4 %7,  %16, off offset:448 sc1\n\t"
      "global_load_dwordx4 %8,  %16, off offset:512 sc1\n\t"
      "global_load_dwordx4 %9,  %16, off offset:576 sc1\n\t"
      "global_load_dwordx4 %10, %16, off offset:640 sc1\n\t"
      "global_load_dwordx4 %11, %16, off offset:704 sc1\n\t"
      "global_load_dwordx4 %12, %16, off offset:768 sc1\n\t"
      "global_load_dwordx4 %13, %16, off offset:832 sc1\n\t"
      "global_load_dwordx4 %14, %16, off offset:896 sc1\n\t"
      "global_load_dwordx4 %15, %16, off offset:960 sc1\n\t"
      "s_waitcnt vmcnt(0)"
      : "=&v"(a[0]), "=&v"(a[1]), "=&v"(a[2]), "=&v"(a[3]),
        "=&v"(a[4]), "=&v"(a[5]), "=&v"(a[6]), "=&v"(a[7]),
        "=&v"(a[8]), "=&v"(a[9]), "=&v"(a[10]), "=&v"(a[11]),
        "=&v"(a[12]), "=&v"(a[13]), "=&v"(a[14]), "=&v"(a[15])
      : "v"(p)
      : "memory");
}

// 4 device-scope short stores (rows erow..erow+3, stride NH*2=1024B) + drain.
__device__ __forceinline__ void store_h4(unsigned short* p, unsigned v0,
                                         unsigned v1, unsigned v2, unsigned v3) {
  asm volatile(
      "global_store_short %0, %1, off sc1\n\t"
      "global_store_short %0, %2, off offset:1024 sc1\n\t"
      "global_store_short %0, %3, off offset:2048 sc1\n\t"
      "global_store_short %0, %4, off offset:3072 sc1\n\t"
      "s_waitcnt vmcnt(0)"
      :
      : "v"(p), "v"(v0), "v"(v1), "v"(v2), "v"(v3)
      : "memory");
}

__device__ __forceinline__ unsigned poll_load_dev(const unsigned* p) {
  unsigned f;
  asm volatile(
      "global_load_dword %0, %1, off sc1\n\t"
      "s_waitcnt vmcnt(0)"
      : "=v"(f) : "v"(p) : "memory");
  return f;
}

// system-scope poll: guaranteed fresh.
__device__ __forceinline__ unsigned poll_load_sys(const unsigned* p) {
  unsigned f;
  asm volatile(
      "global_load_dword %0, %1, off sc0 sc1\n\t"
      "s_waitcnt vmcnt(0)"
      : "=v"(f) : "v"(p) : "memory");
  return f;
}

__device__ __forceinline__ void flag_store(unsigned* p, unsigned v) {
  asm volatile("global_store_dword %0, %1, off sc1"
               :: "v"(p), "v"(v) : "memory");
}
__device__ __forceinline__ void flag_store_sys(unsigned* p, unsigned v) {
  asm volatile("global_store_dword %0, %1, off sc0 sc1"
               :: "v"(p), "v"(v) : "memory");
}
__device__ __forceinline__ void store_short_coh(unsigned short* p, unsigned v) {
  asm volatile("global_store_short %0, %1, off sc0 sc1"
               :: "v"(p), "v"(v) : "memory");
}

// ---------------------------------------------------------------------------
// Fused kernel. Blocks 0..63: recurrence (R14-exact). Blocks 64..255: IG
// producers. Tile T (0..6143): qt=T/1536, b=(T%1536)/12, bn=T%12,
// bm=b*4+qt -> output rows [bm*128,+128) of BT, cols [bn*128,+128) of 3H.
// igflags[bm*12+bn]=1 once the tile is drained.
// ---------------------------------------------------------------------------
template <bool USE_IG>
__global__ __launch_bounds__(256, 1) void gru_fused(
    const float* __restrict__ x, const float* __restrict__ Wih,
    const float* __restrict__ Whh, const float* __restrict__ bias,
    const float* __restrict__ bn, unsigned short* __restrict__ IG,
    unsigned short* __restrict__ hbuf, unsigned* __restrict__ hflags,
    unsigned* __restrict__ igflags, float* __restrict__ hfin) {
  __shared__ unsigned short As[128 * 40];
  __shared__ unsigned short Bs[128 * 40];

  const int tid = threadIdx.x;
  const int lane = tid & 63;
  const int w = tid >> 6;
  const int wm = w >> 1, wn = w & 1;
  const int l15 = lane & 15, q = lane >> 4;

  if (USE_IG && blockIdx.x >= 64) {
    // ---------------- producer path: 192 blocks, 32 tiles each -------------
    const int pid = blockIdx.x - 64;
    for (int T = pid; T < 6144; T += 192) {
      const int qt = T / 1536;
      const int rem = T - qt * 1536;
      const int b = rem / 12;
      const int bnn = rem - b * 12;
      const int bm = b * 4 + qt;

      f32x4 acc[4][4] = {};
      for (int kt = 0; kt < 16; ++kt) {
        __syncthreads();
#pragma unroll
        for (int j = 0; j < 4; ++j) {
          int fi = tid + 256 * j;
          int row = fi >> 3, kq = fi & 7;
          float4 v = *(const float4*)(x + (size_t)(bm * 128 + row) * ND + kt * 32 + kq * 4);
          ushort4 s = {f2bf(v.x), f2bf(v.y), f2bf(v.z), f2bf(v.w)};
          *(ushort4*)&As[row * 40 + kq * 4] = s;
        }
#pragma unroll
        for (int j = 0; j < 4; ++j) {
          int fi = tid + 256 * j;
          int row = fi >> 3, kq = fi & 7;
          float4 v = *(const float4*)(Wih + (size_t)(bnn * 128 + row) * ND + kt * 32 + kq * 4);
          ushort4 s = {f2bf(v.x), f2bf(v.y), f2bf(v.z), f2bf(v.w)};
          *(ushort4*)&Bs[row * 40 + kq * 4] = s;
        }
        __syncthreads();

        short8 af[4], bfv[4];
#pragma unroll
        for (int tm = 0; tm < 4; ++tm)
          af[tm] = *(const short8*)&As[(wm * 64 + tm * 16 + l15) * 40 + q * 8];
#pragma unroll
        for (int tn = 0; tn < 4; ++tn)
          bfv[tn] = *(const short8*)&Bs[(wn * 64 + tn * 16 + l15) * 40 + q * 8];
#pragma unroll
        for (int tm = 0; tm < 4; ++tm)
#pragma unroll
          for (int tn = 0; tn < 4; ++tn)
            acc[tm][tn] = __builtin_amdgcn_mfma_f32_16x16x32_bf16(af[tm], bfv[tn], acc[tm][tn], 0, 0, 0);
      }

      // epilogue: coherent stores -> drain -> tile flag
#pragma unroll
      for (int tm = 0; tm < 4; ++tm) {
#pragma unroll
        for (int tn = 0; tn < 4; ++tn) {
          int ccol = bnn * 128 + wn * 64 + tn * 16 + l15;
          float bb = bias[ccol];
#pragma unroll
          for (int i = 0; i < 4; ++i) {
            int row = bm * 128 + wm * 64 + tm * 16 + q * 4 + i;
            store_short_coh(IG + (size_t)row * NG + ccol,
                            (unsigned)f2bf(acc[tm][tn][i] + bb));
          }
        }
      }
      asm volatile("s_waitcnt vmcnt(0)" ::: "memory");
      __syncthreads();  // all waves drained before the flag goes out
      if (tid == 0) flag_store_sys(igflags + bm * 12 + bnn, 1u);
    }
    return;
  }
  if (!USE_IG && blockIdx.x >= 64) return;

  // ---------------- consumer path: R14-exact h ring + IG quarter gate -----
  const int g = blockIdx.x >> 4;   // 4 groups
  const int c = blockIdx.x & 15;   // 16 col-chunks of 32
  const int b0 = g * 32;
  const int col = c * 32 + wn * 16 + l15;  // this lane's h column
  const int mrow = b0 + wm * 16 + l15;     // A-fragment batch row
  const int erow = b0 + wm * 16 + q * 4;   // C-layout batch row base

  unsigned* const myflag = hflags + ((g * 2 + wm) * 16 + c) * 2 + wn;
  const unsigned* const pollbase = hflags + (g * 2 + wm) * 32;  // 32 flags

  // Whh B-fragments -> registers: 3 gates x 16 k-chunks (192 VGPRs)
  short8 bfr[3][16];
#pragma unroll
  for (int gt = 0; gt < 3; ++gt) {
    const float* src = Whh + (size_t)(gt * NH + col) * NH + q * 8;
#pragma unroll
    for (int kk = 0; kk < 16; ++kk) {
      float4 v0 = *(const float4*)(src + kk * 32);
      float4 v1 = *(const float4*)(src + kk * 32 + 4);
      bfr[gt][kk] = pack8(v0, v1);
    }
  }

  float bi_r = 0.f, bi_z = 0.f, bi_n = 0.f;
  if (!USE_IG) {
    bi_r = bias[col];
    bi_z = bias[NH + col];
    bi_n = bias[2 * NH + col];
  }
  const float bnv = bn[col];

  float hreg[4] = {0.f, 0.f, 0.f, 0.f};

  unsigned short* const hb0 = hbuf;
  unsigned short* const hb1 = hbuf + NB * NH;

  for (int t = 0; t < NT; ++t) {
    const unsigned short* hcur = (t & 1) ? hb1 : hb0;
    unsigned short* hnxt = (t & 1) ? hb0 : hb1;

    // IG quarter gate (4x per run): before ANY touch of this quarter's IG,
    // wait for the tiles covering this block's rows x 3 gate-columns.
    if (USE_IG && (t & 127) == 0) {
      const int qt = t >> 7;
      if (lane < 32) {
        const int bb = b0 + lane;
#pragma unroll
        for (int gi = 0; gi < 3; ++gi) {
          const unsigned* fp = igflags + (size_t)(bb * 4 + qt) * 12 + (c >> 2) + gi * 4;
          unsigned f = poll_load_sys(fp);
          while (f == 0u) f = poll_load_sys(fp);
        }
      }
      // implicit reconvergence before first IG load below
    }

    // IG loads (plain cached; first touch is after the quarter gate).
    float igr[4], igz[4], ign[4];
    if (USE_IG) {
#pragma unroll
      for (int i = 0; i < 4; ++i) {
        const size_t base = ((size_t)(erow + i) * NT + t) * NG + col;
        igr[i] = bf2f(IG[base]);
        igz[i] = bf2f(IG[base + NH]);
        ign[i] = bf2f(IG[base + 2 * NH]);
      }
    }

    int4v araw[16];
    if (t > 0) {
      // wait for the 32 producer waves of this row-half to have written h_t.
      if (lane < 32) {
        const unsigned* fp = pollbase + lane;
        unsigned f = poll_load_dev(fp);
        int tries = 0;
        while ((int)f < t) {
          if (++tries > 8) f = poll_load_sys(fp);
          else             f = poll_load_dev(fp);
        }
      }
      load_h16(hcur + (size_t)mrow * NH + q * 8, araw);
    } else {
#pragma unroll
      for (int kk = 0; kk < 16; ++kk) araw[kk] = (int4v){0, 0, 0, 0};
    }

    f32x4 ar = {0.f, 0.f, 0.f, 0.f};
    f32x4 az = {0.f, 0.f, 0.f, 0.f};
    f32x4 an = {0.f, 0.f, 0.f, 0.f};
    f32x4 ai = {0.f, 0.f, 0.f, 0.f};
#pragma unroll
    for (int kk = 0; kk < 16; ++kk) {
      short8 afk = __builtin_bit_cast(short8, araw[kk]);
      ar = __builtin_amdgcn_mfma_f32_16x16x32_bf16(afk, bfr[0][kk], ar, 0, 0, 0);
      az = __builtin_amdgcn_mfma_f32_16x16x32_bf16(afk, bfr[1][kk], az, 0, 0, 0);
      an = __builtin_amdgcn_mfma_f32_16x16x32_bf16(afk, bfr[2][kk], an, 0, 0, 0);
      if (!USE_IG) {
        const float* xp = x + ((size_t)mrow * NT + t) * ND + kk * 32 + q * 8;
        short8 xa = pack8(*(const float4*)xp, *(const float4*)(xp + 4));
#pragma unroll
        for (int gt = 0; gt < 3; ++gt) {
          const float* wp = Wih + (size_t)(gt * NH + col) * ND + kk * 32 + q * 8;
          short8 wf = pack8(*(const float4*)wp, *(const float4*)(wp + 4));
          if (gt == 0) ar = __builtin_amdgcn_mfma_f32_16x16x32_bf16(xa, wf, ar, 0, 0, 0);
          if (gt == 1) az = __builtin_amdgcn_mfma_f32_16x16x32_bf16(xa, wf, az, 0, 0, 0);
          if (gt == 2) ai = __builtin_amdgcn_mfma_f32_16x16x32_bf16(xa, wf, ai, 0, 0, 0);
        }
      }
    }

    // gates + h update; store, drain, flag (R4/R14 protocol)
    unsigned sv[4];
#pragma unroll
    for (int i = 0; i < 4; ++i) {
      float xr = USE_IG ? (ar[i] + igr[i]) : (ar[i] + bi_r);
      float xz = USE_IG ? (az[i] + igz[i]) : (az[i] + bi_z);
      float xin = USE_IG ? ign[i] : (ai[i] + bi_n);
      float r = sigmoid_f(xr);
      float z = sigmoid_f(xz);
      float n = tanh_f(xin + r * (an[i] + bnv));
      float hn2 = (1.f - z) * n + z * hreg[i];
      hreg[i] = hn2;
      sv[i] = (unsigned)f2bf(hn2);
      if (t == NT - 1) hfin[(size_t)(erow + i) * NH + col] = hn2;
    }
    if (t != NT - 1) {
      store_h4(hnxt + (size_t)erow * NH + col, sv[0], sv[1], sv[2], sv[3]);
      if (lane == 0) flag_store(myflag, (unsigned)(t + 1));
    }
  }
}

// ---------------------------------------------------------------------------
// out = h_T @ Wlin^T + blin; mu = cols [0,256), logvar = cols [256,512).
// ---------------------------------------------------------------------------
__global__ __launch_bounds__(256) void final_linear(
    const float* __restrict__ hfin, const float* __restrict__ Wlin,
    const float* __restrict__ blin, float* __restrict__ out) {
  __shared__ float sh[16 * 516];
  const int tid = threadIdx.x;
  const int b0 = blockIdx.y * 16, o0 = blockIdx.x * 16;

  for (int j = tid; j < 16 * 128; j += 256) {
    int row = j >> 7, kq = j & 127;
    *(float4*)&sh[row * 516 + kq * 4] =
        *(const float4*)(hfin + (size_t)(b0 + row) * NH + kq * 4);
  }
  __syncthreads();

  const int bi = tid & 15, oi = tid >> 4;
  const int o = o0 + oi;
  const float4* wp = (const float4*)(Wlin + (size_t)o * NH);
  float4 a4 = {0.f, 0.f, 0.f, 0.f};
  for (int k4 = 0; k4 < 128; ++k4) {
    float4 wv = wp[k4];
    float4 hv = *(const float4*)&sh[bi * 516 + k4 * 4];
    a4.x += wv.x * hv.x; a4.y += wv.y * hv.y;
    a4.z += wv.z * hv.z; a4.w += wv.w * hv.w;
  }
  float v = a4.x + a4.y + a4.z + a4.w + blin[o];
  int b = b0 + bi;
  if (o < 256) out[b * 256 + o] = v;
  else out[32768 + b * 256 + (o - 256)] = v;
}

// ---------------------------------------------------------------------------
extern "C" void kernel_launch(void* const* d_in, const int* in_sizes, int n_in,
                              void* d_out, int out_size, void* d_ws, size_t ws_size,
                              hipStream_t stream) {
  const float* x    = (const float*)d_in[0];
  const float* Wih  = (const float*)d_in[1];
  const float* Whh  = (const float*)d_in[2];
  const float* bias = (const float*)d_in[3];
  const float* bn   = (const float*)d_in[4];
  const float* Wlin = (const float*)d_in[5];
  const float* blin = (const float*)d_in[6];
  float* out = (float*)d_out;

  char* ws = (char*)d_ws;
  // layout: [hbuf 262144][hflags 1024][igflags 24576][hfin 262144][IG ...]
  unsigned short* hbuf = (unsigned short*)ws;
  unsigned* hflags     = (unsigned*)(ws + 262144);
  unsigned* igflags    = (unsigned*)(ws + 263168);
  float* hfin          = (float*)(ws + 287744);
  unsigned short* IG   = (unsigned short*)(ws + 549888);
  const size_t need_min = 549888;
  const size_t need_ig  = 549888 + (size_t)NB * NT * NG * 2;  // ~203 MB
  if (ws_size < need_min) return;

  // zero hflags + igflags (flag 0 < any live value)
  hipMemsetAsync(ws + 262144, 0, 1024 + 24576, stream);

  const bool useIG = (ws_size >= need_ig);
  if (useIG) {
    gru_fused<true><<<256, 256, 0, stream>>>(x, Wih, Whh, bias, bn, IG,
                                             hbuf, hflags, igflags, hfin);
  } else {
    gru_fused<false><<<64, 256, 0, stream>>>(x, Wih, Whh, bias, bn, nullptr,
                                             hbuf, hflags, igflags, hfin);
  }
  final_linear<<<dim3(32, 8), 256, 0, stream>>>(hfin, Wlin, blin, out);
}